// Round 4
// baseline (3525.051 us; speedup 1.0000x reference)
//
#include <hip/hip_runtime.h>
#include <hip/hip_bf16.h>
#include <stdint.h>

#define D_MODEL 256
#define N_TOK   21760
#define BATCH   2
#define M_TOT   (BATCH*N_TOK)   // 43520 = 340*128
#define NLAY    6

typedef __hip_bfloat16 bf16;
typedef short bf16x8 __attribute__((ext_vector_type(8)));
typedef float f32x4  __attribute__((ext_vector_type(4)));

// packed per-layer weight block (bf16, transposed to [N][K])
#define WVSA_SZ (640*256)
#define WO_SZ   (256*256)
#define W1_SZ   (1024*256)
#define W2_SZ   (256*1024)
#define PER_L   (WVSA_SZ+WO_SZ+W1_SZ+W2_SZ)  // 753664

// ---- workspace layout (aliased by lifetime), total ~231.9 MB ----
#define SZ_QF   ((size_t)M_TOT*256*4)   // 44,564,480
#define SZ_BF   ((size_t)M_TOT*256*2)   // 22,282,240
#define SZ_AW   ((size_t)M_TOT*128*4)   // 22,282,240
#define SZ_WP   ((size_t)PER_L*NLAY*2)  //  9,043,968
#define SZ_BP   ((size_t)NLAY*640*4)    //     15,360
#define OFF_QF    ((size_t)0)
#define OFF_QPOS  (OFF_QF   + SZ_QF)
#define OFF_QB    (OFF_QPOS + SZ_QF)
#define OFF_QPB   (OFF_QB   + SZ_BF)    // also `sampled`
#define OFF_WP    (OFF_QPB  + SZ_BF)
#define OFF_BP    (OFF_WP   + SZ_WP)
#define OFF_R1    (OFF_BP   + SZ_BP)    // offb | hidden chunk (44.56 MB)
#define OFF_VAL   (OFF_R1   + SZ_QF)
#define OFF_AW    (OFF_VAL  + SZ_BF)
#define WS_NEED   (OFF_AW   + SZ_AW)    // 231,881,728 bytes

// ---------------------------------------------------------------- sentinel
__global__ void sentinel_kernel(float* out) { out[0] = 1.0e6f; }

// ---------------------------------------------------------------- pack
__global__ void pack_kernel(const float* __restrict__ Wv, const float* __restrict__ Ws,
                            const float* __restrict__ Wa, const float* __restrict__ Wo,
                            const float* __restrict__ W1, const float* __restrict__ W2,
                            const float* __restrict__ bv, const float* __restrict__ bso,
                            const float* __restrict__ ba,
                            bf16* __restrict__ wp, float* __restrict__ bp)
{
    const int WTOT = PER_L * NLAY;
    for (int idx = blockIdx.x*blockDim.x + threadIdx.x; idx < WTOT + NLAY*640;
         idx += gridDim.x*blockDim.x) {
        if (idx < WTOT) {
            int l = idx / PER_L, r = idx - l*PER_L;
            float v;
            if (r < WVSA_SZ) {                       // Wvsa_t[640][256]
                int n = r >> 8, k = r & 255;
                if (n < 256)      v = Wv[((size_t)l*256+k)*256 + n];
                else if (n < 512) v = Ws[((size_t)l*256+k)*256 + (n-256)];
                else              v = Wa[((size_t)l*256+k)*128 + (n-512)];
            } else if (r < WVSA_SZ+WO_SZ) {          // Wo_t[256][256]
                int j = r - WVSA_SZ; int n = j >> 8, k = j & 255;
                v = Wo[((size_t)l*256+k)*256 + n];
            } else if (r < WVSA_SZ+WO_SZ+W1_SZ) {    // W1_t[1024][256]
                int j = r - (WVSA_SZ+WO_SZ); int n = j >> 8, k = j & 255;
                v = W1[((size_t)l*256+k)*1024 + n];
            } else {                                 // W2_t[256][1024]
                int j = r - (WVSA_SZ+WO_SZ+W1_SZ); int n = j >> 10, k = j & 1023;
                v = W2[((size_t)l*1024+k)*256 + n];
            }
            wp[idx] = __float2bfloat16(v);
        } else {
            int i = idx - WTOT; int l = i / 640, n = i - l*640;
            float v = (n < 256) ? bv[l*256+n]
                    : (n < 512) ? bso[l*256+(n-256)]
                                : ba[l*128+(n-512)];
            bp[l*640+n] = v;
        }
    }
}

// ---------------------------------------------------------------- prep (src transpose)
__device__ __forceinline__ void tile_decode(int st, int& lvl, int& s0, int& hw, int& start)
{
    if (st < 256)      { lvl=0; s0=st*64;       hw=16384; start=0; }
    else if (st < 320) { lvl=1; s0=(st-256)*64; hw=4096;  start=16384; }
    else if (st < 336) { lvl=2; s0=(st-320)*64; hw=1024;  start=20480; }
    else               { lvl=3; s0=(st-336)*64; hw=256;   start=21504; }
}

__global__ __launch_bounds__(256) void prep_pos_kernel(
    const float* __restrict__ p0, const float* __restrict__ p1,
    const float* __restrict__ p2, const float* __restrict__ p3,
    const float* __restrict__ le, float* __restrict__ qpos)
{
    __shared__ float tile[32][65];
    int lvl, s0, hw, start; tile_decode(blockIdx.x, lvl, s0, hw, start);
    const float* sp = lvl==0?p0 : lvl==1?p1 : lvl==2?p2 : p3;
    const int t = threadIdx.x, b = blockIdx.z, c0 = blockIdx.y*32;
#pragma unroll
    for (int j=0;j<8;++j){
        int cl = j*4 + (t>>6), sl = t&63;
        tile[cl][sl] = sp[((size_t)b*256 + c0+cl)*hw + s0 + sl];
    }
    __syncthreads();
#pragma unroll
    for (int j=0;j<8;++j){
        int sl = j*8 + (t>>5), cl = t&31;
        float v = tile[cl][sl] + le[lvl*256 + c0 + cl];
        size_t o = ((size_t)b*N_TOK + start + s0 + sl)*256 + c0 + cl;
        qpos[o] = v;
    }
}

__global__ __launch_bounds__(256) void prep_q_kernel(
    const float* __restrict__ s0p, const float* __restrict__ s1p,
    const float* __restrict__ s2p, const float* __restrict__ s3p,
    const float* __restrict__ qpos, float* __restrict__ qf,
    bf16* __restrict__ qb, bf16* __restrict__ qpb)
{
    __shared__ float tile[32][65];
    int lvl, s0, hw, start; tile_decode(blockIdx.x, lvl, s0, hw, start);
    const float* sp = lvl==0?s0p : lvl==1?s1p : lvl==2?s2p : s3p;
    const int t = threadIdx.x, b = blockIdx.z, c0 = blockIdx.y*32;
#pragma unroll
    for (int j=0;j<8;++j){
        int cl = j*4 + (t>>6), sl = t&63;
        tile[cl][sl] = sp[((size_t)b*256 + c0+cl)*hw + s0 + sl];
    }
    __syncthreads();
#pragma unroll
    for (int j=0;j<8;++j){
        int sl = j*8 + (t>>5), cl = t&31;
        float v = tile[cl][sl];
        size_t o = ((size_t)b*N_TOK + start + s0 + sl)*256 + c0 + cl;
        qf[o] = v;
        qb[o] = __float2bfloat16(v);
        qpb[o] = __float2bfloat16(v + qpos[o]);
    }
}

// ---------------------------------------------------------------- GEMM (bf16 MFMA)
// C[M][N] = A[M][K](bf16) * Wt[N][K]^T(bf16) + bias, 128x128 tile, 4 waves 2x2.
// MODE 0: N=640 split -> value bf16 [M][256] | off f32 [M][256] | aw f32 [M][128];
//         A = qb for n<256, qpb otherwise.
// MODE 1: f32 out [M][256].
// MODE 2: relu -> bf16 out [M][1024].
template<int MODE>
__global__ __launch_bounds__(256) void gemm_kernel(
    const bf16* __restrict__ A, const bf16* __restrict__ A2,
    const bf16* __restrict__ Wt, const float* __restrict__ bias,
    int K, void* __restrict__ out0, void* __restrict__ out1, void* __restrict__ out2)
{
    __shared__ ushort As[128][40];   // +8 pad -> 80B row stride, 2-way conflict (free)
    __shared__ ushort Bs[128][40];
    const int tid = threadIdx.x;
    const int lane = tid & 63, wid = tid >> 6;
    const int wr = wid >> 1, wc = wid & 1;
    const int lr = lane & 15, lg = lane >> 4;
    const size_t m0 = (size_t)blockIdx.x * 128;
    const int n0 = blockIdx.y * 128;
    const bf16* Ause = (MODE == 0 && n0 >= 256) ? A2 : A;

    f32x4 acc[4][4];
#pragma unroll
    for (int i=0;i<4;++i)
#pragma unroll
        for (int j=0;j<4;++j) acc[i][j] = (f32x4){0.f,0.f,0.f,0.f};

    for (int k0 = 0; k0 < K; k0 += 32) {
#pragma unroll
        for (int c = tid; c < 512; c += 256) {
            int row = c >> 2, seg = c & 3;
            *(uint4*)&As[row][seg*8] = *(const uint4*)&Ause[(m0+row)*K + k0 + seg*8];
            *(uint4*)&Bs[row][seg*8] = *(const uint4*)&Wt[((size_t)(n0+row))*K + k0 + seg*8];
        }
        __syncthreads();
        bf16x8 av[4], bw[4];
#pragma unroll
        for (int i=0;i<4;++i){
            av[i] = *(bf16x8*)&As[wr*64 + i*16 + lr][lg*8];
            bw[i] = *(bf16x8*)&Bs[wc*64 + i*16 + lr][lg*8];
        }
#pragma unroll
        for (int mi=0;mi<4;++mi)
#pragma unroll
            for (int ni=0;ni<4;++ni)
                acc[mi][ni] = __builtin_amdgcn_mfma_f32_16x16x32_bf16(av[mi], bw[ni], acc[mi][ni], 0,0,0);
        __syncthreads();
    }
    // epilogue: D row = (lane>>4)*4 + r, col = lane&15   [measured: learn_hip m89]
#pragma unroll
    for (int mi=0;mi<4;++mi){
#pragma unroll
        for (int ni=0;ni<4;++ni){
            int gr0 = (int)m0 + wr*64 + mi*16 + lg*4;
            int gc  = n0 + wc*64 + ni*16 + lr;
            float bb = bias[gc];
#pragma unroll
            for (int r=0;r<4;++r){
                float y = acc[mi][ni][r] + bb;
                size_t row = (size_t)(gr0 + r);
                if (MODE == 0) {
                    if (gc < 256)      ((bf16*)out0)[row*256 + gc] = __float2bfloat16(y);
                    else if (gc < 512) ((float*)out1)[row*256 + (gc-256)] = y;
                    else               ((float*)out2)[row*128 + (gc-512)] = y;
                } else if (MODE == 1) {
                    ((float*)out0)[row*256 + gc] = y;
                } else {
                    ((bf16*)out0)[row*1024 + gc] = __float2bfloat16(fmaxf(y, 0.f));
                }
            }
        }
    }
}

// ---------------------------------------------------------------- deformable sampling
__global__ __launch_bounds__(256) void sample_kernel(
    const bf16* __restrict__ value, const float* __restrict__ offb,
    const float* __restrict__ awb, bf16* __restrict__ sampled)
{
    __shared__ float off_s[256];
    __shared__ float w_s[128];
    const int m = blockIdx.x, t = threadIdx.x;
    off_s[t] = offb[(size_t)m*256 + t];
    if (t < 128) {
        float lgt = awb[(size_t)m*128 + t];
        float mx = lgt;
#pragma unroll
        for (int o=1;o<16;o<<=1) mx = fmaxf(mx, __shfl_xor(mx, o));
        float e = __expf(lgt - mx);
        float sm = e;
#pragma unroll
        for (int o=1;o<16;o<<=1) sm += __shfl_xor(sm, o);
        w_s[t] = e / sm;
    }
    __syncthreads();

    const int b = m / N_TOK;
    const int n = m - b*N_TOK;
    float refx, refy;
    if (n < 16384)      { int s=n;       int qy=s>>7, qx=s&127; refx=(qx+0.5f)*(1.f/128.f); refy=(qy+0.5f)*(1.f/128.f); }
    else if (n < 20480) { int s=n-16384; int qy=s>>6, qx=s&63;  refx=(qx+0.5f)*(1.f/64.f);  refy=(qy+0.5f)*(1.f/64.f); }
    else if (n < 21504) { int s=n-20480; int qy=s>>5, qx=s&31;  refx=(qx+0.5f)*(1.f/32.f);  refy=(qy+0.5f)*(1.f/32.f); }
    else                { int s=n-21504; int qy=s>>4, qx=s&15;  refx=(qx+0.5f)*(1.f/16.f);  refy=(qy+0.5f)*(1.f/16.f); }

    const int h = t >> 5, d = t & 31;
    const bf16* vb = value + (size_t)b*N_TOK*256 + h*32 + d;
    const int LSTART[4] = {0, 16384, 20480, 21504};
    float acc = 0.f;
#pragma unroll
    for (int lvl=0; lvl<4; ++lvl){
        const int wl = 128 >> lvl;
        const bf16* base = vb + (size_t)LSTART[lvl]*256;
        const float bx = refx*(float)wl - 0.5f, by = refy*(float)wl - 0.5f;
#pragma unroll
        for (int p=0;p<4;++p){
            const int oi = (((h<<2)+lvl)<<3) + (p<<1);
            float fx = bx + off_s[oi];
            float fy = by + off_s[oi+1];
            float wgt = w_s[(h<<4) + (lvl<<2) + p];
            float x0f = floorf(fx), y0f = floorf(fy);
            float dx = fx - x0f, dy = fy - y0f;
            int ix = (int)x0f, iy = (int)y0f;
            int cx0 = min(max(ix,0),   wl-1), cx1 = min(max(ix+1,0), wl-1);
            int cy0 = min(max(iy,0),   wl-1), cy1 = min(max(iy+1,0), wl-1);
            bool vx0 = (unsigned)ix     < (unsigned)wl, vx1 = (unsigned)(ix+1) < (unsigned)wl;
            bool vy0 = (unsigned)iy     < (unsigned)wl, vy1 = (unsigned)(iy+1) < (unsigned)wl;
            float v00 = __bfloat162float(base[(size_t)(cy0*wl+cx0)*256]); if(!(vx0&&vy0)) v00=0.f;
            float v01 = __bfloat162float(base[(size_t)(cy0*wl+cx1)*256]); if(!(vx1&&vy0)) v01=0.f;
            float v10 = __bfloat162float(base[(size_t)(cy1*wl+cx0)*256]); if(!(vx0&&vy1)) v10=0.f;
            float v11 = __bfloat162float(base[(size_t)(cy1*wl+cx1)*256]); if(!(vx1&&vy1)) v11=0.f;
            acc += wgt * ((1.f-dx)*(1.f-dy)*v00 + dx*(1.f-dy)*v01
                        + (1.f-dx)*dy*v10 + dx*dy*v11);
        }
    }
    sampled[(size_t)m*256 + t] = __float2bfloat16(acc);
}

// ---------------------------------------------------------------- residual + LN
__global__ __launch_bounds__(256) void ln_kernel(
    const float* __restrict__ xin, const float* __restrict__ delta,
    const float* __restrict__ g, const float* __restrict__ be,
    const float* __restrict__ qpos, float* __restrict__ qf,
    bf16* __restrict__ qb, bf16* __restrict__ qpb, float* __restrict__ dout)
{
    const int m = blockIdx.x, t = threadIdx.x;
    const size_t o = (size_t)m*256 + t;
    float x = xin[o] + delta[o];
    float s1 = x, s2 = x*x;
#pragma unroll
    for (int i=1;i<64;i<<=1){ s1 += __shfl_xor(s1,i); s2 += __shfl_xor(s2,i); }
    __shared__ float p1[4], p2[4];
    if ((t & 63) == 0){ p1[t>>6] = s1; p2[t>>6] = s2; }
    __syncthreads();
    s1 = p1[0]+p1[1]+p1[2]+p1[3];
    s2 = p2[0]+p2[1]+p2[2]+p2[3];
    float mu  = s1 * (1.f/256.f);
    float var = s2 * (1.f/256.f) - mu*mu;
    float y = (x - mu) * rsqrtf(var + 1e-5f) * g[t] + be[t];
    qf[o]  = y;
    qb[o]  = __float2bfloat16(y);
    qpb[o] = __float2bfloat16(y + qpos[o]);
    if (dout) dout[o] = y;
}

// ---------------------------------------------------------------- launch
extern "C" void kernel_launch(void* const* d_in, const int* in_sizes, int n_in,
                              void* d_out, int out_size, void* d_ws, size_t ws_size,
                              hipStream_t stream)
{
    // setup_inputs() dict order is INTERLEAVED: src0,pos0,src1,pos1,src2,pos2,src3,pos3
    const float* src0 = (const float*)d_in[0];
    const float* pos0 = (const float*)d_in[1];
    const float* src1 = (const float*)d_in[2];
    const float* pos1 = (const float*)d_in[3];
    const float* src2 = (const float*)d_in[4];
    const float* pos2 = (const float*)d_in[5];
    const float* src3 = (const float*)d_in[6];
    const float* pos3 = (const float*)d_in[7];
    const float* le   = (const float*)d_in[8];
    const float* Wv   = (const float*)d_in[9];
    const float* bv   = (const float*)d_in[10];
    const float* Ws   = (const float*)d_in[11];
    const float* bso  = (const float*)d_in[12];
    const float* Wa   = (const float*)d_in[13];
    const float* ba   = (const float*)d_in[14];
    const float* Wo   = (const float*)d_in[15];
    const float* bo   = (const float*)d_in[16];
    const float* g1   = (const float*)d_in[17];
    const float* be1  = (const float*)d_in[18];
    const float* W1   = (const float*)d_in[19];
    const float* b1   = (const float*)d_in[20];
    const float* W2   = (const float*)d_in[21];
    const float* b2   = (const float*)d_in[22];
    const float* g2   = (const float*)d_in[23];
    const float* be2  = (const float*)d_in[24];

    if (ws_size < WS_NEED) {   // diagnostic: absmax ~1e6 means ws too small
        sentinel_kernel<<<1, 1, 0, stream>>>((float*)d_out);
        return;
    }
    char* ws = (char*)d_ws;
    float* qf     = (float*)(ws + OFF_QF);
    float* qpos   = (float*)(ws + OFF_QPOS);
    bf16*  qb     = (bf16*) (ws + OFF_QB);
    bf16*  qpb    = (bf16*) (ws + OFF_QPB);
    bf16*  sampled= (bf16*) (ws + OFF_QPB);   // alias: qpb dead gemm0->ln1
    bf16*  wp     = (bf16*) (ws + OFF_WP);
    float* bp     = (float*)(ws + OFF_BP);
    float* offb   = (float*)(ws + OFF_R1);    // gemm0 -> sample
    bf16*  hidden = (bf16*) (ws + OFF_R1);    // gemm2 -> gemm3 chunk (disjoint lifetime)
    bf16*  value  = (bf16*) (ws + OFF_VAL);
    float* awb    = (float*)(ws + OFF_AW);
    float* gout   = (float*)d_out;            // gemm1/gemm3 -> ln (read-before-write)

    pack_kernel<<<dim3(4096), 256, 0, stream>>>(Wv, Ws, Wa, Wo, W1, W2, bv, bso, ba, wp, bp);
    prep_pos_kernel<<<dim3(340,8,2), 256, 0, stream>>>(pos0,pos1,pos2,pos3, le, qpos);
    prep_q_kernel<<<dim3(340,8,2), 256, 0, stream>>>(src0,src1,src2,src3, qpos, qf, qb, qpb);

    for (int l = 0; l < NLAY; ++l) {
        const bf16* wl_ = wp + (size_t)l*PER_L;
        gemm_kernel<0><<<dim3(340,5), 256, 0, stream>>>(qb, qpb, wl_, bp + l*640, 256,
                                                        value, offb, awb);
        sample_kernel<<<dim3(M_TOT), 256, 0, stream>>>(value, offb, awb, sampled);
        gemm_kernel<1><<<dim3(340,2), 256, 0, stream>>>(sampled, nullptr, wl_ + WVSA_SZ,
                                                        bo + l*256, 256, gout, nullptr, nullptr);
        ln_kernel<<<dim3(M_TOT), 256, 0, stream>>>(qf, gout, g1 + l*256, be1 + l*256, qpos,
                                                   qf, qb, qpb, nullptr);
        // FFN, chunked x2 so hidden (44.56 MB) aliases the dead offb region
        for (int c = 0; c < 2; ++c) {
            const size_t mo = (size_t)c * (M_TOT/2);
            gemm_kernel<2><<<dim3(170,8), 256, 0, stream>>>(qb + mo*256, nullptr,
                                                            wl_ + WVSA_SZ + WO_SZ,
                                                            b1 + l*1024, 256, hidden, nullptr, nullptr);
            gemm_kernel<1><<<dim3(170,2), 256, 0, stream>>>(hidden, nullptr,
                                                            wl_ + WVSA_SZ + WO_SZ + W1_SZ,
                                                            b2 + l*256, 1024, gout + mo*256, nullptr, nullptr);
        }
        ln_kernel<<<dim3(M_TOT), 256, 0, stream>>>(qf, gout, g2 + l*256, be2 + l*256, qpos,
                                                   qf, qb, qpb, (l==NLAY-1) ? (float*)d_out : nullptr);
    }
}

// Round 5
// 2311.604 us; speedup vs baseline: 1.5249x; 1.5249x over previous
//
#include <hip/hip_runtime.h>
#include <hip/hip_bf16.h>
#include <stdint.h>

#define D_MODEL 256
#define N_TOK   21760
#define BATCH   2
#define M_TOT   (BATCH*N_TOK)   // 43520 = 340*128
#define NLAY    6

typedef __hip_bfloat16 bf16;
typedef short bf16x8 __attribute__((ext_vector_type(8)));
typedef float f32x4  __attribute__((ext_vector_type(4)));

// packed per-layer weight block (bf16, transposed to [N][K])
#define WVSA_SZ (640*256)
#define WO_SZ   (256*256)
#define W1_SZ   (1024*256)
#define W2_SZ   (256*1024)
#define PER_L   (WVSA_SZ+WO_SZ+W1_SZ+W2_SZ)  // 753664

// ---- workspace layout (aliased by lifetime), total ~231.9 MB ----
#define SZ_QF   ((size_t)M_TOT*256*4)   // 44,564,480
#define SZ_BF   ((size_t)M_TOT*256*2)   // 22,282,240
#define SZ_AW   ((size_t)M_TOT*128*4)   // 22,282,240
#define SZ_WP   ((size_t)PER_L*NLAY*2)  //  9,043,968
#define SZ_BP   ((size_t)NLAY*640*4)    //     15,360
#define OFF_QF    ((size_t)0)
#define OFF_QPOS  (OFF_QF   + SZ_QF)
#define OFF_QB    (OFF_QPOS + SZ_QF)
#define OFF_QPB   (OFF_QB   + SZ_BF)    // also `sampled`
#define OFF_WP    (OFF_QPB  + SZ_BF)
#define OFF_BP    (OFF_WP   + SZ_WP)
#define OFF_R1    (OFF_BP   + SZ_BP)    // offb | hidden chunk (44.56 MB)
#define OFF_VAL   (OFF_R1   + SZ_QF)
#define OFF_AW    (OFF_VAL  + SZ_BF)
#define WS_NEED   (OFF_AW   + SZ_AW)    // 231,881,728 bytes

// ---------------------------------------------------------------- sentinel
__global__ void sentinel_kernel(float* out) { out[0] = 1.0e6f; }

// ---------------------------------------------------------------- pack
__global__ void pack_kernel(const float* __restrict__ Wv, const float* __restrict__ Ws,
                            const float* __restrict__ Wa, const float* __restrict__ Wo,
                            const float* __restrict__ W1, const float* __restrict__ W2,
                            const float* __restrict__ bv, const float* __restrict__ bso,
                            const float* __restrict__ ba,
                            bf16* __restrict__ wp, float* __restrict__ bp)
{
    const int WTOT = PER_L * NLAY;
    for (int idx = blockIdx.x*blockDim.x + threadIdx.x; idx < WTOT + NLAY*640;
         idx += gridDim.x*blockDim.x) {
        if (idx < WTOT) {
            int l = idx / PER_L, r = idx - l*PER_L;
            float v;
            if (r < WVSA_SZ) {                       // Wvsa_t[640][256]
                int n = r >> 8, k = r & 255;
                if (n < 256)      v = Wv[((size_t)l*256+k)*256 + n];
                else if (n < 512) v = Ws[((size_t)l*256+k)*256 + (n-256)];
                else              v = Wa[((size_t)l*256+k)*128 + (n-512)];
            } else if (r < WVSA_SZ+WO_SZ) {          // Wo_t[256][256]
                int j = r - WVSA_SZ; int n = j >> 8, k = j & 255;
                v = Wo[((size_t)l*256+k)*256 + n];
            } else if (r < WVSA_SZ+WO_SZ+W1_SZ) {    // W1_t[1024][256]
                int j = r - (WVSA_SZ+WO_SZ); int n = j >> 8, k = j & 255;
                v = W1[((size_t)l*256+k)*1024 + n];
            } else {                                 // W2_t[256][1024]
                int j = r - (WVSA_SZ+WO_SZ+W1_SZ); int n = j >> 10, k = j & 1023;
                v = W2[((size_t)l*1024+k)*256 + n];
            }
            wp[idx] = __float2bfloat16(v);
        } else {
            int i = idx - WTOT; int l = i / 640, n = i - l*640;
            float v = (n < 256) ? bv[l*256+n]
                    : (n < 512) ? bso[l*256+(n-256)]
                                : ba[l*128+(n-512)];
            bp[l*640+n] = v;
        }
    }
}

// ---------------------------------------------------------------- prep (src transpose)
__device__ __forceinline__ void tile_decode(int st, int& lvl, int& s0, int& hw, int& start)
{
    if (st < 256)      { lvl=0; s0=st*64;       hw=16384; start=0; }
    else if (st < 320) { lvl=1; s0=(st-256)*64; hw=4096;  start=16384; }
    else if (st < 336) { lvl=2; s0=(st-320)*64; hw=1024;  start=20480; }
    else               { lvl=3; s0=(st-336)*64; hw=256;   start=21504; }
}

__global__ __launch_bounds__(256) void prep_pos_kernel(
    const float* __restrict__ p0, const float* __restrict__ p1,
    const float* __restrict__ p2, const float* __restrict__ p3,
    const float* __restrict__ le, float* __restrict__ qpos)
{
    __shared__ float tile[32][65];
    int lvl, s0, hw, start; tile_decode(blockIdx.x, lvl, s0, hw, start);
    const float* sp = lvl==0?p0 : lvl==1?p1 : lvl==2?p2 : p3;
    const int t = threadIdx.x, b = blockIdx.z, c0 = blockIdx.y*32;
#pragma unroll
    for (int j=0;j<8;++j){
        int cl = j*4 + (t>>6), sl = t&63;
        tile[cl][sl] = sp[((size_t)b*256 + c0+cl)*hw + s0 + sl];
    }
    __syncthreads();
#pragma unroll
    for (int j=0;j<8;++j){
        int sl = j*8 + (t>>5), cl = t&31;
        float v = tile[cl][sl] + le[lvl*256 + c0 + cl];
        size_t o = ((size_t)b*N_TOK + start + s0 + sl)*256 + c0 + cl;
        qpos[o] = v;
    }
}

__global__ __launch_bounds__(256) void prep_q_kernel(
    const float* __restrict__ s0p, const float* __restrict__ s1p,
    const float* __restrict__ s2p, const float* __restrict__ s3p,
    const float* __restrict__ qpos, float* __restrict__ qf,
    bf16* __restrict__ qb, bf16* __restrict__ qpb)
{
    __shared__ float tile[32][65];
    int lvl, s0, hw, start; tile_decode(blockIdx.x, lvl, s0, hw, start);
    const float* sp = lvl==0?s0p : lvl==1?s1p : lvl==2?s2p : s3p;
    const int t = threadIdx.x, b = blockIdx.z, c0 = blockIdx.y*32;
#pragma unroll
    for (int j=0;j<8;++j){
        int cl = j*4 + (t>>6), sl = t&63;
        tile[cl][sl] = sp[((size_t)b*256 + c0+cl)*hw + s0 + sl];
    }
    __syncthreads();
#pragma unroll
    for (int j=0;j<8;++j){
        int sl = j*8 + (t>>5), cl = t&31;
        float v = tile[cl][sl];
        size_t o = ((size_t)b*N_TOK + start + s0 + sl)*256 + c0 + cl;
        qf[o] = v;
        qb[o] = __float2bfloat16(v);
        qpb[o] = __float2bfloat16(v + qpos[o]);
    }
}

// ---------------------------------------------------------------- GEMM (bf16 MFMA)
// C[M][N] = A[M][K](bf16) * Wt[N][K]^T(bf16) + bias, 128x128 tile, 4 waves 2x2.
template<int MODE>
__global__ __launch_bounds__(256) void gemm_kernel(
    const bf16* __restrict__ A, const bf16* __restrict__ A2,
    const bf16* __restrict__ Wt, const float* __restrict__ bias,
    int K, void* __restrict__ out0, void* __restrict__ out1, void* __restrict__ out2)
{
    __shared__ ushort As[128][40];   // +8 pad -> 80B row stride, 2-way conflict (free)
    __shared__ ushort Bs[128][40];
    const int tid = threadIdx.x;
    const int lane = tid & 63, wid = tid >> 6;
    const int wr = wid >> 1, wc = wid & 1;
    const int lr = lane & 15, lg = lane >> 4;
    const size_t m0 = (size_t)blockIdx.x * 128;
    const int n0 = blockIdx.y * 128;
    const bf16* Ause = (MODE == 0 && n0 >= 256) ? A2 : A;

    f32x4 acc[4][4];
#pragma unroll
    for (int i=0;i<4;++i)
#pragma unroll
        for (int j=0;j<4;++j) acc[i][j] = (f32x4){0.f,0.f,0.f,0.f};

    for (int k0 = 0; k0 < K; k0 += 32) {
#pragma unroll
        for (int c = tid; c < 512; c += 256) {
            int row = c >> 2, seg = c & 3;
            *(uint4*)&As[row][seg*8] = *(const uint4*)&Ause[(m0+row)*K + k0 + seg*8];
            *(uint4*)&Bs[row][seg*8] = *(const uint4*)&Wt[((size_t)(n0+row))*K + k0 + seg*8];
        }
        __syncthreads();
        bf16x8 av[4], bw[4];
#pragma unroll
        for (int i=0;i<4;++i){
            av[i] = *(bf16x8*)&As[wr*64 + i*16 + lr][lg*8];
            bw[i] = *(bf16x8*)&Bs[wc*64 + i*16 + lr][lg*8];
        }
#pragma unroll
        for (int mi=0;mi<4;++mi)
#pragma unroll
            for (int ni=0;ni<4;++ni)
                acc[mi][ni] = __builtin_amdgcn_mfma_f32_16x16x32_bf16(av[mi], bw[ni], acc[mi][ni], 0,0,0);
        __syncthreads();
    }
    // epilogue: D row = (lane>>4)*4 + r, col = lane&15   [measured: learn_hip m89]
#pragma unroll
    for (int mi=0;mi<4;++mi){
#pragma unroll
        for (int ni=0;ni<4;++ni){
            int gr0 = (int)m0 + wr*64 + mi*16 + lg*4;
            int gc  = n0 + wc*64 + ni*16 + lr;
            float bb = bias[gc];
#pragma unroll
            for (int r=0;r<4;++r){
                float y = acc[mi][ni][r] + bb;
                size_t row = (size_t)(gr0 + r);
                if (MODE == 0) {
                    if (gc < 256)      ((bf16*)out0)[row*256 + gc] = __float2bfloat16(y);
                    else if (gc < 512) ((float*)out1)[row*256 + (gc-256)] = y;
                    else               ((float*)out2)[row*128 + (gc-512)] = y;
                } else if (MODE == 1) {
                    ((float*)out0)[row*256 + gc] = y;
                } else {
                    ((bf16*)out0)[row*1024 + gc] = __float2bfloat16(fmaxf(y, 0.f));
                }
            }
        }
    }
}

// ---------------------------------------------------------------- deformable sampling
// One wave per token: lane = h*8 + c; each lane owns 4 channels (ushort4 gathers,
// f32x4 accumulator). Weight math computed once per 8 lanes instead of per 32.
__device__ __forceinline__ float bf16_lo(uint u){ return __uint_as_float(u << 16); }
__device__ __forceinline__ float bf16_hi(uint u){ return __uint_as_float(u & 0xffff0000u); }

__global__ __launch_bounds__(256) void sample_kernel(
    const bf16* __restrict__ value, const float* __restrict__ offb,
    const float* __restrict__ awb, bf16* __restrict__ sampled)
{
    __shared__ float off_s[4][256];
    __shared__ float w_s[4][128];
    const int wv = threadIdx.x >> 6, lane = threadIdx.x & 63;
    const int m = blockIdx.x*4 + wv;

    // stage offsets: one float4 per lane
    *(float4*)&off_s[wv][lane*4] = *(const float4*)&offb[(size_t)m*256 + lane*4];
    // softmax: 2 logits per lane; each head's 16 logits live in an 8-lane group
    float2 lgt = *(const float2*)&awb[(size_t)m*128 + lane*2];
    float mx = fmaxf(lgt.x, lgt.y);
#pragma unroll
    for (int o=1;o<8;o<<=1) mx = fmaxf(mx, __shfl_xor(mx, o));
    float e0 = __expf(lgt.x - mx), e1 = __expf(lgt.y - mx);
    float sm = e0 + e1;
#pragma unroll
    for (int o=1;o<8;o<<=1) sm += __shfl_xor(sm, o);
    float rs = __frcp_rn(sm);
    w_s[wv][lane*2]   = e0 * rs;
    w_s[wv][lane*2+1] = e1 * rs;
    __syncthreads();

    const int b = m / N_TOK;
    const int n = m - b*N_TOK;
    float refx, refy;
    if (n < 16384)      { int s=n;       int qy=s>>7, qx=s&127; refx=(qx+0.5f)*(1.f/128.f); refy=(qy+0.5f)*(1.f/128.f); }
    else if (n < 20480) { int s=n-16384; int qy=s>>6, qx=s&63;  refx=(qx+0.5f)*(1.f/64.f);  refy=(qy+0.5f)*(1.f/64.f); }
    else if (n < 21504) { int s=n-20480; int qy=s>>5, qx=s&31;  refx=(qx+0.5f)*(1.f/32.f);  refy=(qy+0.5f)*(1.f/32.f); }
    else                { int s=n-21504; int qy=s>>4, qx=s&15;  refx=(qx+0.5f)*(1.f/16.f);  refy=(qy+0.5f)*(1.f/16.f); }

    const int h = lane >> 3, c = lane & 7;           // head, channel-group (4 ch)
    const bf16* vb = value + (size_t)b*N_TOK*256 + h*32 + c*4;
    const int LSTART[4] = {0, 16384, 20480, 21504};
    f32x4 acc = (f32x4){0.f,0.f,0.f,0.f};
#pragma unroll
    for (int lvl=0; lvl<4; ++lvl){
        const int wl = 128 >> lvl;
        const bf16* base = vb + (size_t)LSTART[lvl]*256;
        const float bx = refx*(float)wl - 0.5f, by = refy*(float)wl - 0.5f;
#pragma unroll
        for (int p=0;p<4;++p){
            const int oi = (((h<<2)+lvl)<<3) + (p<<1);
            float fx = bx + off_s[wv][oi];
            float fy = by + off_s[wv][oi+1];
            float wgt = w_s[wv][(h<<4) + (lvl<<2) + p];
            float x0f = floorf(fx), y0f = floorf(fy);
            float dx = fx - x0f, dy = fy - y0f;
            int ix = (int)x0f, iy = (int)y0f;
            int cx0 = min(max(ix,0),   wl-1), cx1 = min(max(ix+1,0), wl-1);
            int cy0 = min(max(iy,0),   wl-1), cy1 = min(max(iy+1,0), wl-1);
            bool vx0 = (unsigned)ix     < (unsigned)wl, vx1 = (unsigned)(ix+1) < (unsigned)wl;
            bool vy0 = (unsigned)iy     < (unsigned)wl, vy1 = (unsigned)(iy+1) < (unsigned)wl;
            float w00 = (vx0&&vy0) ? (1.f-dx)*(1.f-dy)*wgt : 0.f;
            float w01 = (vx1&&vy0) ? dx*(1.f-dy)*wgt       : 0.f;
            float w10 = (vx0&&vy1) ? (1.f-dx)*dy*wgt       : 0.f;
            float w11 = (vx1&&vy1) ? dx*dy*wgt             : 0.f;
            uint2 q00 = *(const uint2*)&base[(size_t)(cy0*wl+cx0)*256];
            uint2 q01 = *(const uint2*)&base[(size_t)(cy0*wl+cx1)*256];
            uint2 q10 = *(const uint2*)&base[(size_t)(cy1*wl+cx0)*256];
            uint2 q11 = *(const uint2*)&base[(size_t)(cy1*wl+cx1)*256];
            acc[0] += w00*bf16_lo(q00.x) + w01*bf16_lo(q01.x) + w10*bf16_lo(q10.x) + w11*bf16_lo(q11.x);
            acc[1] += w00*bf16_hi(q00.x) + w01*bf16_hi(q01.x) + w10*bf16_hi(q10.x) + w11*bf16_hi(q11.x);
            acc[2] += w00*bf16_lo(q00.y) + w01*bf16_lo(q01.y) + w10*bf16_lo(q10.y) + w11*bf16_lo(q11.y);
            acc[3] += w00*bf16_hi(q00.y) + w01*bf16_hi(q01.y) + w10*bf16_hi(q10.y) + w11*bf16_hi(q11.y);
        }
    }
    ushort4 outv;
    outv.x = __bfloat16_as_ushort(__float2bfloat16(acc[0]));
    outv.y = __bfloat16_as_ushort(__float2bfloat16(acc[1]));
    outv.z = __bfloat16_as_ushort(__float2bfloat16(acc[2]));
    outv.w = __bfloat16_as_ushort(__float2bfloat16(acc[3]));
    *(ushort4*)&sampled[(size_t)m*256 + h*32 + c*4] = outv;
}

// ---------------------------------------------------------------- residual + LN
__global__ __launch_bounds__(256) void ln_kernel(
    const float* __restrict__ xin, const float* __restrict__ delta,
    const float* __restrict__ g, const float* __restrict__ be,
    const float* __restrict__ qpos, float* __restrict__ qf,
    bf16* __restrict__ qb, bf16* __restrict__ qpb, float* __restrict__ dout)
{
    const int m = blockIdx.x, t = threadIdx.x;
    const size_t o = (size_t)m*256 + t;
    float x = xin[o] + delta[o];
    float s1 = x, s2 = x*x;
#pragma unroll
    for (int i=1;i<64;i<<=1){ s1 += __shfl_xor(s1,i); s2 += __shfl_xor(s2,i); }
    __shared__ float p1[4], p2[4];
    if ((t & 63) == 0){ p1[t>>6] = s1; p2[t>>6] = s2; }
    __syncthreads();
    s1 = p1[0]+p1[1]+p1[2]+p1[3];
    s2 = p2[0]+p2[1]+p2[2]+p2[3];
    float mu  = s1 * (1.f/256.f);
    float var = s2 * (1.f/256.f) - mu*mu;
    float y = (x - mu) * rsqrtf(var + 1e-5f) * g[t] + be[t];
    qf[o]  = y;
    qb[o]  = __float2bfloat16(y);
    qpb[o] = __float2bfloat16(y + qpos[o]);
    if (dout) dout[o] = y;
}

// ---------------------------------------------------------------- launch
extern "C" void kernel_launch(void* const* d_in, const int* in_sizes, int n_in,
                              void* d_out, int out_size, void* d_ws, size_t ws_size,
                              hipStream_t stream)
{
    // setup_inputs() dict order is INTERLEAVED: src0,pos0,src1,pos1,...
    const float* src0 = (const float*)d_in[0];
    const float* pos0 = (const float*)d_in[1];
    const float* src1 = (const float*)d_in[2];
    const float* pos1 = (const float*)d_in[3];
    const float* src2 = (const float*)d_in[4];
    const float* pos2 = (const float*)d_in[5];
    const float* src3 = (const float*)d_in[6];
    const float* pos3 = (const float*)d_in[7];
    const float* le   = (const float*)d_in[8];
    const float* Wv   = (const float*)d_in[9];
    const float* bv   = (const float*)d_in[10];
    const float* Ws   = (const float*)d_in[11];
    const float* bso  = (const float*)d_in[12];
    const float* Wa   = (const float*)d_in[13];
    const float* ba   = (const float*)d_in[14];
    const float* Wo   = (const float*)d_in[15];
    const float* bo   = (const float*)d_in[16];
    const float* g1   = (const float*)d_in[17];
    const float* be1  = (const float*)d_in[18];
    const float* W1   = (const float*)d_in[19];
    const float* b1   = (const float*)d_in[20];
    const float* W2   = (const float*)d_in[21];
    const float* b2   = (const float*)d_in[22];
    const float* g2   = (const float*)d_in[23];
    const float* be2  = (const float*)d_in[24];

    if (ws_size < WS_NEED) {   // diagnostic: absmax ~1e6 means ws too small
        sentinel_kernel<<<1, 1, 0, stream>>>((float*)d_out);
        return;
    }
    char* ws = (char*)d_ws;
    float* qf     = (float*)(ws + OFF_QF);
    float* qpos   = (float*)(ws + OFF_QPOS);
    bf16*  qb     = (bf16*) (ws + OFF_QB);
    bf16*  qpb    = (bf16*) (ws + OFF_QPB);
    bf16*  sampled= (bf16*) (ws + OFF_QPB);   // alias: qpb dead gemm0->ln1
    bf16*  wp     = (bf16*) (ws + OFF_WP);
    float* bp     = (float*)(ws + OFF_BP);
    float* offb   = (float*)(ws + OFF_R1);    // gemm0 -> sample
    bf16*  hidden = (bf16*) (ws + OFF_R1);    // gemm2 -> gemm3 chunk (disjoint lifetime)
    bf16*  value  = (bf16*) (ws + OFF_VAL);
    float* awb    = (float*)(ws + OFF_AW);
    float* gout   = (float*)d_out;            // gemm1/gemm3 -> ln (read-before-write)

    pack_kernel<<<dim3(4096), 256, 0, stream>>>(Wv, Ws, Wa, Wo, W1, W2, bv, bso, ba, wp, bp);
    prep_pos_kernel<<<dim3(340,8,2), 256, 0, stream>>>(pos0,pos1,pos2,pos3, le, qpos);
    prep_q_kernel<<<dim3(340,8,2), 256, 0, stream>>>(src0,src1,src2,src3, qpos, qf, qb, qpb);

    for (int l = 0; l < NLAY; ++l) {
        const bf16* wl_ = wp + (size_t)l*PER_L;
        gemm_kernel<0><<<dim3(340,5), 256, 0, stream>>>(qb, qpb, wl_, bp + l*640, 256,
                                                        value, offb, awb);
        sample_kernel<<<dim3(M_TOT/4), 256, 0, stream>>>(value, offb, awb, sampled);
        gemm_kernel<1><<<dim3(340,2), 256, 0, stream>>>(sampled, nullptr, wl_ + WVSA_SZ,
                                                        bo + l*256, 256, gout, nullptr, nullptr);
        ln_kernel<<<dim3(M_TOT), 256, 0, stream>>>(qf, gout, g1 + l*256, be1 + l*256, qpos,
                                                   qf, qb, qpb, nullptr);
        // FFN, chunked x2 so hidden (44.56 MB) aliases the dead offb region
        for (int c = 0; c < 2; ++c) {
            const size_t mo = (size_t)c * (M_TOT/2);
            gemm_kernel<2><<<dim3(170,8), 256, 0, stream>>>(qb + mo*256, nullptr,
                                                            wl_ + WVSA_SZ + WO_SZ,
                                                            b1 + l*1024, 256, hidden, nullptr, nullptr);
            gemm_kernel<1><<<dim3(170,2), 256, 0, stream>>>(hidden, nullptr,
                                                            wl_ + WVSA_SZ + WO_SZ + W1_SZ,
                                                            b2 + l*256, 1024, gout + mo*256, nullptr, nullptr);
        }
        ln_kernel<<<dim3(M_TOT), 256, 0, stream>>>(qf, gout, g2 + l*256, be2 + l*256, qpos,
                                                   qf, qb, qpb, (l==NLAY-1) ? (float*)d_out : nullptr);
    }
}

// Round 6
// 2183.125 us; speedup vs baseline: 1.6147x; 1.0589x over previous
//
#include <hip/hip_runtime.h>
#include <hip/hip_bf16.h>
#include <stdint.h>

#define D_MODEL 256
#define N_TOK   21760
#define BATCH   2
#define M_TOT   (BATCH*N_TOK)   // 43520 = 340*128
#define NLAY    6

typedef __hip_bfloat16 bf16;
typedef short bf16x8 __attribute__((ext_vector_type(8)));
typedef float f32x4  __attribute__((ext_vector_type(4)));

// packed per-layer weight block (bf16, transposed to [N][K])
#define WVSA_SZ (640*256)
#define WO_SZ   (256*256)
#define W1_SZ   (1024*256)
#define W2_SZ   (256*1024)
#define PER_L   (WVSA_SZ+WO_SZ+W1_SZ+W2_SZ)  // 753664

// ---- workspace layout (aliased by lifetime), total ~209.6 MB ----
#define SZ_QF   ((size_t)M_TOT*256*4)   // 44,564,480
#define SZ_BF   ((size_t)M_TOT*256*2)   // 22,282,240
#define SZ_AW   ((size_t)M_TOT*128*4)   // 22,282,240
#define SZ_WP   ((size_t)PER_L*NLAY*2)  //  9,043,968
#define SZ_BP   ((size_t)NLAY*640*4)    //     15,360
#define OFF_QF    ((size_t)0)
#define OFF_QPOS  (OFF_QF   + SZ_QF)    // bf16 now
#define OFF_QB    (OFF_QPOS + SZ_BF)
#define OFF_QPB   (OFF_QB   + SZ_BF)    // also `sampled`
#define OFF_WP    (OFF_QPB  + SZ_BF)
#define OFF_BP    (OFF_WP   + SZ_WP)
#define OFF_R1    (OFF_BP   + SZ_BP)    // offb | hidden chunk (44.56 MB)
#define OFF_VAL   (OFF_R1   + SZ_QF)
#define OFF_AW    (OFF_VAL  + SZ_BF)
#define WS_NEED   (OFF_AW   + SZ_AW)

// ---------------------------------------------------------------- helpers
typedef const __attribute__((address_space(1))) void gvoid_t;
typedef __attribute__((address_space(3))) void lvoid_t;
__device__ __forceinline__ void gload_lds16(const void* g, void* l){
    __builtin_amdgcn_global_load_lds((gvoid_t*)g, (lvoid_t*)l, 16, 0, 0);
}

// ---------------------------------------------------------------- sentinel
__global__ void sentinel_kernel(float* out) { out[0] = 1.0e6f; }

// ---------------------------------------------------------------- pack
__global__ void pack_kernel(const float* __restrict__ Wv, const float* __restrict__ Ws,
                            const float* __restrict__ Wa, const float* __restrict__ Wo,
                            const float* __restrict__ W1, const float* __restrict__ W2,
                            const float* __restrict__ bv, const float* __restrict__ bso,
                            const float* __restrict__ ba,
                            bf16* __restrict__ wp, float* __restrict__ bp)
{
    const int WTOT = PER_L * NLAY;
    for (int idx = blockIdx.x*blockDim.x + threadIdx.x; idx < WTOT + NLAY*640;
         idx += gridDim.x*blockDim.x) {
        if (idx < WTOT) {
            int l = idx / PER_L, r = idx - l*PER_L;
            float v;
            if (r < WVSA_SZ) {                       // Wvsa_t[640][256]
                int n = r >> 8, k = r & 255;
                if (n < 256)      v = Wv[((size_t)l*256+k)*256 + n];
                else if (n < 512) v = Ws[((size_t)l*256+k)*256 + (n-256)];
                else              v = Wa[((size_t)l*256+k)*128 + (n-512)];
            } else if (r < WVSA_SZ+WO_SZ) {          // Wo_t[256][256]
                int j = r - WVSA_SZ; int n = j >> 8, k = j & 255;
                v = Wo[((size_t)l*256+k)*256 + n];
            } else if (r < WVSA_SZ+WO_SZ+W1_SZ) {    // W1_t[1024][256]
                int j = r - (WVSA_SZ+WO_SZ); int n = j >> 8, k = j & 255;
                v = W1[((size_t)l*256+k)*1024 + n];
            } else {                                 // W2_t[256][1024]
                int j = r - (WVSA_SZ+WO_SZ+W1_SZ); int n = j >> 10, k = j & 1023;
                v = W2[((size_t)l*1024+k)*256 + n];
            }
            wp[idx] = __float2bfloat16(v);
        } else {
            int i = idx - WTOT; int l = i / 640, n = i - l*640;
            float v = (n < 256) ? bv[l*256+n]
                    : (n < 512) ? bso[l*256+(n-256)]
                                : ba[l*128+(n-512)];
            bp[l*640+n] = v;
        }
    }
}

// ---------------------------------------------------------------- prep (src transpose)
__device__ __forceinline__ void tile_decode(int st, int& lvl, int& s0, int& hw, int& start)
{
    if (st < 256)      { lvl=0; s0=st*64;       hw=16384; start=0; }
    else if (st < 320) { lvl=1; s0=(st-256)*64; hw=4096;  start=16384; }
    else if (st < 336) { lvl=2; s0=(st-320)*64; hw=1024;  start=20480; }
    else               { lvl=3; s0=(st-336)*64; hw=256;   start=21504; }
}

__global__ __launch_bounds__(256) void prep_pos_kernel(
    const float* __restrict__ p0, const float* __restrict__ p1,
    const float* __restrict__ p2, const float* __restrict__ p3,
    const float* __restrict__ le, bf16* __restrict__ qpos)
{
    __shared__ float tile[32][65];
    int lvl, s0, hw, start; tile_decode(blockIdx.x, lvl, s0, hw, start);
    const float* sp = lvl==0?p0 : lvl==1?p1 : lvl==2?p2 : p3;
    const int t = threadIdx.x, b = blockIdx.z, c0 = blockIdx.y*32;
#pragma unroll
    for (int j=0;j<8;++j){
        int cl = j*4 + (t>>6), sl = t&63;
        tile[cl][sl] = sp[((size_t)b*256 + c0+cl)*hw + s0 + sl];
    }
    __syncthreads();
#pragma unroll
    for (int j=0;j<8;++j){
        int sl = j*8 + (t>>5), cl = t&31;
        float v = tile[cl][sl] + le[lvl*256 + c0 + cl];
        size_t o = ((size_t)b*N_TOK + start + s0 + sl)*256 + c0 + cl;
        qpos[o] = __float2bfloat16(v);
    }
}

__global__ __launch_bounds__(256) void prep_q_kernel(
    const float* __restrict__ s0p, const float* __restrict__ s1p,
    const float* __restrict__ s2p, const float* __restrict__ s3p,
    const bf16* __restrict__ qpos, float* __restrict__ qf,
    bf16* __restrict__ qb, bf16* __restrict__ qpb)
{
    __shared__ float tile[32][65];
    int lvl, s0, hw, start; tile_decode(blockIdx.x, lvl, s0, hw, start);
    const float* sp = lvl==0?s0p : lvl==1?s1p : lvl==2?s2p : s3p;
    const int t = threadIdx.x, b = blockIdx.z, c0 = blockIdx.y*32;
#pragma unroll
    for (int j=0;j<8;++j){
        int cl = j*4 + (t>>6), sl = t&63;
        tile[cl][sl] = sp[((size_t)b*256 + c0+cl)*hw + s0 + sl];
    }
    __syncthreads();
#pragma unroll
    for (int j=0;j<8;++j){
        int sl = j*8 + (t>>5), cl = t&31;
        float v = tile[cl][sl];
        size_t o = ((size_t)b*N_TOK + start + s0 + sl)*256 + c0 + cl;
        qf[o] = v;
        qb[o] = __float2bfloat16(v);
        qpb[o] = __float2bfloat16(v + __bfloat162float(qpos[o]));
    }
}

// ---------------------------------------------------------------- GEMM (bf16 MFMA)
// C[M][N] = A[M][K](bf16) * Wt[N][K]^T(bf16) + bias, 128x128 tile, 4 waves 2x2.
// Staging: global_load_lds dwordx4, linear LDS [128][32], source pre-swizzled
// (slot ^= (row>>1)&3) and same XOR on ds_read (rule 21: both-sides-or-neither).
template<int MODE>
__global__ __launch_bounds__(256) void gemm_kernel(
    const bf16* __restrict__ A, const bf16* __restrict__ A2,
    const bf16* __restrict__ Wt, const float* __restrict__ bias,
    int K, void* __restrict__ out0, void* __restrict__ out1, void* __restrict__ out2)
{
    __shared__ __align__(1024) ushort As[128*32];
    __shared__ __align__(1024) ushort Bs[128*32];
    const int tid = threadIdx.x;
    const int lane = tid & 63, w = tid >> 6;
    const int wr = w >> 1, wc = w & 1;
    const int lr = lane & 15, lg = lane >> 4;
    const size_t m0 = (size_t)blockIdx.x * 128;
    const int n0 = blockIdx.y * 128;
    const bf16* Ause = (MODE == 0 && n0 >= 256) ? A2 : A;

    // staging geometry: wave w covers rows [w*32, w*32+32) in 2 instrs of 1KB
    const int srow0 = (w<<5) + (lane>>2);     // j=0 row for this lane
    const int sphys = (lane&3);               // physical 16B slot in row

    f32x4 acc[4][4];
#pragma unroll
    for (int i=0;i<4;++i)
#pragma unroll
        for (int j=0;j<4;++j) acc[i][j] = (f32x4){0.f,0.f,0.f,0.f};

    for (int k0 = 0; k0 < K; k0 += 32) {
#pragma unroll
        for (int j=0;j<2;++j){
            int row  = srow0 + j*16;
            int slot = sphys ^ ((row>>1)&3);  // pre-swizzled global source
            gload_lds16(&Ause[(m0+row)*(size_t)K + k0 + slot*8], &As[row*32 + sphys*8]);
            gload_lds16(&Wt[(size_t)(n0+row)*K + k0 + slot*8],   &Bs[row*32 + sphys*8]);
        }
        asm volatile("s_waitcnt vmcnt(0)" ::: "memory");
        __syncthreads();
        bf16x8 av[4], bw[4];
#pragma unroll
        for (int i=0;i<4;++i){
            int ar = wr*64 + i*16 + lr;
            int br = wc*64 + i*16 + lr;
            av[i] = *(bf16x8*)&As[ar*32 + ((lg ^ ((ar>>1)&3))<<3)];
            bw[i] = *(bf16x8*)&Bs[br*32 + ((lg ^ ((br>>1)&3))<<3)];
        }
#pragma unroll
        for (int mi=0;mi<4;++mi)
#pragma unroll
            for (int ni=0;ni<4;++ni)
                acc[mi][ni] = __builtin_amdgcn_mfma_f32_16x16x32_bf16(av[mi], bw[ni], acc[mi][ni], 0,0,0);
        __syncthreads();
    }
    // epilogue: D row = (lane>>4)*4 + r, col = lane&15   [measured: learn_hip m89]
#pragma unroll
    for (int mi=0;mi<4;++mi){
#pragma unroll
        for (int ni=0;ni<4;++ni){
            int gr0 = (int)m0 + wr*64 + mi*16 + lg*4;
            int gc  = n0 + wc*64 + ni*16 + lr;
            float bb = bias[gc];
#pragma unroll
            for (int r=0;r<4;++r){
                float y = acc[mi][ni][r] + bb;
                size_t row = (size_t)(gr0 + r);
                if (MODE == 0) {
                    if (gc < 256)      ((bf16*)out0)[row*256 + gc] = __float2bfloat16(y);
                    else if (gc < 512) ((float*)out1)[row*256 + (gc-256)] = y;
                    else               ((float*)out2)[row*128 + (gc-512)] = y;
                } else if (MODE == 1) {
                    ((float*)out0)[row*256 + gc] = y;
                } else {
                    ((bf16*)out0)[row*1024 + gc] = __float2bfloat16(fmaxf(y, 0.f));
                }
            }
        }
    }
}

// ---------------------------------------------------------------- deformable sampling
// One wave per token; lane = h*8 + c; 4 channels per lane (ushort4 gathers).
// LDS padded to head-stride 33/17 words -> distinct banks across 8 heads.
__device__ __forceinline__ float bf16_lo(uint u){ return __uint_as_float(u << 16); }
__device__ __forceinline__ float bf16_hi(uint u){ return __uint_as_float(u & 0xffff0000u); }

__global__ __launch_bounds__(256) void sample_kernel(
    const bf16* __restrict__ value, const float* __restrict__ offb,
    const float* __restrict__ awb, bf16* __restrict__ sampled)
{
    __shared__ float off_s[4][264];   // 8 heads * 33
    __shared__ float w_s[4][136];     // 8 heads * 17
    const int wv = threadIdx.x >> 6, lane = threadIdx.x & 63;
    const int m = blockIdx.x*4 + wv;
    const int h = lane >> 3;

    {   // stage offsets with +1-word pad per head
        float4 o4 = *(const float4*)&offb[(size_t)m*256 + lane*4];
        int r = (lane*4) & 31;
        off_s[wv][h*33 + r]     = o4.x;
        off_s[wv][h*33 + r + 1] = o4.y;
        off_s[wv][h*33 + r + 2] = o4.z;
        off_s[wv][h*33 + r + 3] = o4.w;
    }
    // softmax: 2 logits/lane, head = 8-lane group
    float2 lgt = *(const float2*)&awb[(size_t)m*128 + lane*2];
    float mx = fmaxf(lgt.x, lgt.y);
#pragma unroll
    for (int o=1;o<8;o<<=1) mx = fmaxf(mx, __shfl_xor(mx, o));
    float e0 = __expf(lgt.x - mx), e1 = __expf(lgt.y - mx);
    float sm = e0 + e1;
#pragma unroll
    for (int o=1;o<8;o<<=1) sm += __shfl_xor(sm, o);
    float rs = __frcp_rn(sm);
    {
        int idx = (lane*2) & 15;
        w_s[wv][h*17 + idx]     = e0 * rs;
        w_s[wv][h*17 + idx + 1] = e1 * rs;
    }
    __syncthreads();

    const int b = m / N_TOK;
    const int n = m - b*N_TOK;
    float refx, refy;
    if (n < 16384)      { int s=n;       int qy=s>>7, qx=s&127; refx=(qx+0.5f)*(1.f/128.f); refy=(qy+0.5f)*(1.f/128.f); }
    else if (n < 20480) { int s=n-16384; int qy=s>>6, qx=s&63;  refx=(qx+0.5f)*(1.f/64.f);  refy=(qy+0.5f)*(1.f/64.f); }
    else if (n < 21504) { int s=n-20480; int qy=s>>5, qx=s&31;  refx=(qx+0.5f)*(1.f/32.f);  refy=(qy+0.5f)*(1.f/32.f); }
    else                { int s=n-21504; int qy=s>>4, qx=s&15;  refx=(qx+0.5f)*(1.f/16.f);  refy=(qy+0.5f)*(1.f/16.f); }

    const int c = lane & 7;           // channel-group (4 ch)
    const bf16* vb = value + (size_t)b*N_TOK*256 + h*32 + c*4;
    const int LSTART[4] = {0, 16384, 20480, 21504};
    f32x4 acc = (f32x4){0.f,0.f,0.f,0.f};
#pragma unroll
    for (int lvl=0; lvl<4; ++lvl){
        const int wl = 128 >> lvl;
        const bf16* base = vb + (size_t)LSTART[lvl]*256;
        const float bx = refx*(float)wl - 0.5f, by = refy*(float)wl - 0.5f;
#pragma unroll
        for (int p=0;p<4;++p){
            const int oi = h*33 + (lvl<<3) + (p<<1);
            float fx = bx + off_s[wv][oi];
            float fy = by + off_s[wv][oi+1];
            float wgt = w_s[wv][h*17 + (lvl<<2) + p];
            float x0f = floorf(fx), y0f = floorf(fy);
            float dx = fx - x0f, dy = fy - y0f;
            int ix = (int)x0f, iy = (int)y0f;
            int cx0 = min(max(ix,0),   wl-1), cx1 = min(max(ix+1,0), wl-1);
            int cy0 = min(max(iy,0),   wl-1), cy1 = min(max(iy+1,0), wl-1);
            bool vx0 = (unsigned)ix     < (unsigned)wl, vx1 = (unsigned)(ix+1) < (unsigned)wl;
            bool vy0 = (unsigned)iy     < (unsigned)wl, vy1 = (unsigned)(iy+1) < (unsigned)wl;
            float w00 = (vx0&&vy0) ? (1.f-dx)*(1.f-dy)*wgt : 0.f;
            float w01 = (vx1&&vy0) ? dx*(1.f-dy)*wgt       : 0.f;
            float w10 = (vx0&&vy1) ? (1.f-dx)*dy*wgt       : 0.f;
            float w11 = (vx1&&vy1) ? dx*dy*wgt             : 0.f;
            uint2 q00 = *(const uint2*)&base[(size_t)(cy0*wl+cx0)*256];
            uint2 q01 = *(const uint2*)&base[(size_t)(cy0*wl+cx1)*256];
            uint2 q10 = *(const uint2*)&base[(size_t)(cy1*wl+cx0)*256];
            uint2 q11 = *(const uint2*)&base[(size_t)(cy1*wl+cx1)*256];
            acc[0] += w00*bf16_lo(q00.x) + w01*bf16_lo(q01.x) + w10*bf16_lo(q10.x) + w11*bf16_lo(q11.x);
            acc[1] += w00*bf16_hi(q00.x) + w01*bf16_hi(q01.x) + w10*bf16_hi(q10.x) + w11*bf16_hi(q11.x);
            acc[2] += w00*bf16_lo(q00.y) + w01*bf16_lo(q01.y) + w10*bf16_lo(q10.y) + w11*bf16_lo(q11.y);
            acc[3] += w00*bf16_hi(q00.y) + w01*bf16_hi(q01.y) + w10*bf16_hi(q10.y) + w11*bf16_hi(q11.y);
        }
    }
    ushort4 outv;
    outv.x = __bfloat16_as_ushort(__float2bfloat16(acc[0]));
    outv.y = __bfloat16_as_ushort(__float2bfloat16(acc[1]));
    outv.z = __bfloat16_as_ushort(__float2bfloat16(acc[2]));
    outv.w = __bfloat16_as_ushort(__float2bfloat16(acc[3]));
    *(ushort4*)&sampled[(size_t)m*256 + h*32 + c*4] = outv;
}

// ---------------------------------------------------------------- residual + LN
__global__ __launch_bounds__(256) void ln_kernel(
    const float* __restrict__ xin, const float* __restrict__ delta,
    const float* __restrict__ g, const float* __restrict__ be,
    const bf16* __restrict__ qpos, float* __restrict__ qf,
    bf16* __restrict__ qb, bf16* __restrict__ qpb, float* __restrict__ dout)
{
    const int m = blockIdx.x, t = threadIdx.x;
    const size_t o = (size_t)m*256 + t;
    float x = xin[o] + delta[o];
    float s1 = x, s2 = x*x;
#pragma unroll
    for (int i=1;i<64;i<<=1){ s1 += __shfl_xor(s1,i); s2 += __shfl_xor(s2,i); }
    __shared__ float p1[4], p2[4];
    if ((t & 63) == 0){ p1[t>>6] = s1; p2[t>>6] = s2; }
    __syncthreads();
    s1 = p1[0]+p1[1]+p1[2]+p1[3];
    s2 = p2[0]+p2[1]+p2[2]+p2[3];
    float mu  = s1 * (1.f/256.f);
    float var = s2 * (1.f/256.f) - mu*mu;
    float y = (x - mu) * rsqrtf(var + 1e-5f) * g[t] + be[t];
    qf[o]  = y;
    qb[o]  = __float2bfloat16(y);
    qpb[o] = __float2bfloat16(y + __bfloat162float(qpos[o]));
    if (dout) dout[o] = y;
}

// ---------------------------------------------------------------- launch
extern "C" void kernel_launch(void* const* d_in, const int* in_sizes, int n_in,
                              void* d_out, int out_size, void* d_ws, size_t ws_size,
                              hipStream_t stream)
{
    // setup_inputs() dict order is INTERLEAVED: src0,pos0,src1,pos1,...
    const float* src0 = (const float*)d_in[0];
    const float* pos0 = (const float*)d_in[1];
    const float* src1 = (const float*)d_in[2];
    const float* pos1 = (const float*)d_in[3];
    const float* src2 = (const float*)d_in[4];
    const float* pos2 = (const float*)d_in[5];
    const float* src3 = (const float*)d_in[6];
    const float* pos3 = (const float*)d_in[7];
    const float* le   = (const float*)d_in[8];
    const float* Wv   = (const float*)d_in[9];
    const float* bv   = (const float*)d_in[10];
    const float* Ws   = (const float*)d_in[11];
    const float* bso  = (const float*)d_in[12];
    const float* Wa   = (const float*)d_in[13];
    const float* ba   = (const float*)d_in[14];
    const float* Wo   = (const float*)d_in[15];
    const float* bo   = (const float*)d_in[16];
    const float* g1   = (const float*)d_in[17];
    const float* be1  = (const float*)d_in[18];
    const float* W1   = (const float*)d_in[19];
    const float* b1   = (const float*)d_in[20];
    const float* W2   = (const float*)d_in[21];
    const float* b2   = (const float*)d_in[22];
    const float* g2   = (const float*)d_in[23];
    const float* be2  = (const float*)d_in[24];

    if (ws_size < WS_NEED) {   // diagnostic: absmax ~1e6 means ws too small
        sentinel_kernel<<<1, 1, 0, stream>>>((float*)d_out);
        return;
    }
    char* ws = (char*)d_ws;
    float* qf     = (float*)(ws + OFF_QF);
    bf16*  qpos   = (bf16*) (ws + OFF_QPOS);
    bf16*  qb     = (bf16*) (ws + OFF_QB);
    bf16*  qpb    = (bf16*) (ws + OFF_QPB);
    bf16*  sampled= (bf16*) (ws + OFF_QPB);   // alias: qpb dead gemm0->ln1
    bf16*  wp     = (bf16*) (ws + OFF_WP);
    float* bp     = (float*)(ws + OFF_BP);
    float* offb   = (float*)(ws + OFF_R1);    // gemm0 -> sample
    bf16*  hidden = (bf16*) (ws + OFF_R1);    // gemm2 -> gemm3 chunk (disjoint lifetime)
    bf16*  value  = (bf16*) (ws + OFF_VAL);
    float* awb    = (float*)(ws + OFF_AW);
    float* gout   = (float*)d_out;            // gemm1/gemm3 -> ln (read-before-write)

    pack_kernel<<<dim3(4096), 256, 0, stream>>>(Wv, Ws, Wa, Wo, W1, W2, bv, bso, ba, wp, bp);
    prep_pos_kernel<<<dim3(340,8,2), 256, 0, stream>>>(pos0,pos1,pos2,pos3, le, qpos);
    prep_q_kernel<<<dim3(340,8,2), 256, 0, stream>>>(src0,src1,src2,src3, qpos, qf, qb, qpb);

    for (int l = 0; l < NLAY; ++l) {
        const bf16* wl_ = wp + (size_t)l*PER_L;
        gemm_kernel<0><<<dim3(340,5), 256, 0, stream>>>(qb, qpb, wl_, bp + l*640, 256,
                                                        value, offb, awb);
        sample_kernel<<<dim3(M_TOT/4), 256, 0, stream>>>(value, offb, awb, sampled);
        gemm_kernel<1><<<dim3(340,2), 256, 0, stream>>>(sampled, nullptr, wl_ + WVSA_SZ,
                                                        bo + l*256, 256, gout, nullptr, nullptr);
        ln_kernel<<<dim3(M_TOT), 256, 0, stream>>>(qf, gout, g1 + l*256, be1 + l*256, qpos,
                                                   qf, qb, qpb, nullptr);
        // FFN, chunked x2 so hidden (44.56 MB) aliases the dead offb region
        for (int c = 0; c < 2; ++c) {
            const size_t mo = (size_t)c * (M_TOT/2);
            gemm_kernel<2><<<dim3(170,8), 256, 0, stream>>>(qb + mo*256, nullptr,
                                                            wl_ + WVSA_SZ + WO_SZ,
                                                            b1 + l*1024, 256, hidden, nullptr, nullptr);
            gemm_kernel<1><<<dim3(170,2), 256, 0, stream>>>(hidden, nullptr,
                                                            wl_ + WVSA_SZ + WO_SZ + W1_SZ,
                                                            b2 + l*256, 1024, gout + mo*256, nullptr, nullptr);
        }
        ln_kernel<<<dim3(M_TOT), 256, 0, stream>>>(qf, gout, g2 + l*256, be2 + l*256, qpos,
                                                   qf, qb, qpb, (l==NLAY-1) ? (float*)d_out : nullptr);
    }
}

// Round 7
// 1894.726 us; speedup vs baseline: 1.8605x; 1.1522x over previous
//
#include <hip/hip_runtime.h>
#include <hip/hip_bf16.h>
#include <stdint.h>

#define D_MODEL 256
#define N_TOK   21760
#define BATCH   2
#define M_TOT   (BATCH*N_TOK)   // 43520 = 340*128
#define NLAY    6

typedef __hip_bfloat16 bf16;
typedef short bf16x8 __attribute__((ext_vector_type(8)));
typedef float f32x4  __attribute__((ext_vector_type(4)));

// packed per-layer weight block (bf16, transposed to [N][K])
#define WVSA_SZ (640*256)
#define WO_SZ   (256*256)
#define W1_SZ   (1024*256)
#define W2_SZ   (256*1024)
#define PER_L   (WVSA_SZ+WO_SZ+W1_SZ+W2_SZ)  // 753664

// ---- workspace layout (aliased by lifetime), total ~165.4 MB ----
// bf16 residual stream: qb IS the q stream (no separate f32 copy).
// delta (bf16 attn/ffn output) aliases the dead `value` region.
// offb | hidden-chunk share R1. sampled aliases qpb.
#define SZ_QF   ((size_t)M_TOT*256*4)   // 44,564,480 (offb f32 / hidden chunk)
#define SZ_BF   ((size_t)M_TOT*256*2)   // 22,282,240
#define SZ_AW   ((size_t)M_TOT*128*4)   // 22,282,240
#define SZ_WP   ((size_t)PER_L*NLAY*2)  //  9,043,968
#define SZ_BP   ((size_t)NLAY*640*4)    //     15,360
#define OFF_QPOS  ((size_t)0)
#define OFF_QB    (OFF_QPOS + SZ_BF)
#define OFF_QPB   (OFF_QB   + SZ_BF)    // also `sampled`
#define OFF_WP    (OFF_QPB  + SZ_BF)
#define OFF_BP    (OFF_WP   + SZ_WP)
#define OFF_R1    (OFF_BP   + SZ_BP)    // offb f32 | hidden chunk (44.56 MB)
#define OFF_VAL   (OFF_R1   + SZ_QF)    // value bf16 | delta bf16 (22.28 MB)
#define OFF_AW    (OFF_VAL  + SZ_BF)
#define WS_NEED   (OFF_AW   + SZ_AW)

// ---------------------------------------------------------------- helpers
typedef const __attribute__((address_space(1))) void gvoid_t;
typedef __attribute__((address_space(3))) void lvoid_t;
__device__ __forceinline__ void gload_lds16(const void* g, void* l){
    __builtin_amdgcn_global_load_lds((gvoid_t*)g, (lvoid_t*)l, 16, 0, 0);
}
__device__ __forceinline__ float bfu(ushort u){ return __uint_as_float(((uint)u)<<16); }
__device__ __forceinline__ ushort f2b(float f){ return __bfloat16_as_ushort(__float2bfloat16(f)); }

// ---------------------------------------------------------------- sentinel
__global__ void sentinel_kernel(float* out) { out[0] = 1.0e6f; }

// ---------------------------------------------------------------- pack
__global__ void pack_kernel(const float* __restrict__ Wv, const float* __restrict__ Ws,
                            const float* __restrict__ Wa, const float* __restrict__ Wo,
                            const float* __restrict__ W1, const float* __restrict__ W2,
                            const float* __restrict__ bv, const float* __restrict__ bso,
                            const float* __restrict__ ba,
                            bf16* __restrict__ wp, float* __restrict__ bp)
{
    const int WTOT = PER_L * NLAY;
    for (int idx = blockIdx.x*blockDim.x + threadIdx.x; idx < WTOT + NLAY*640;
         idx += gridDim.x*blockDim.x) {
        if (idx < WTOT) {
            int l = idx / PER_L, r = idx - l*PER_L;
            float v;
            if (r < WVSA_SZ) {                       // Wvsa_t[640][256]
                int n = r >> 8, k = r & 255;
                if (n < 256)      v = Wv[((size_t)l*256+k)*256 + n];
                else if (n < 512) v = Ws[((size_t)l*256+k)*256 + (n-256)];
                else              v = Wa[((size_t)l*256+k)*128 + (n-512)];
            } else if (r < WVSA_SZ+WO_SZ) {          // Wo_t[256][256]
                int j = r - WVSA_SZ; int n = j >> 8, k = j & 255;
                v = Wo[((size_t)l*256+k)*256 + n];
            } else if (r < WVSA_SZ+WO_SZ+W1_SZ) {    // W1_t[1024][256]
                int j = r - (WVSA_SZ+WO_SZ); int n = j >> 8, k = j & 255;
                v = W1[((size_t)l*256+k)*1024 + n];
            } else {                                 // W2_t[256][1024]
                int j = r - (WVSA_SZ+WO_SZ+W1_SZ); int n = j >> 10, k = j & 1023;
                v = W2[((size_t)l*1024+k)*256 + n];
            }
            wp[idx] = __float2bfloat16(v);
        } else {
            int i = idx - WTOT; int l = i / 640, n = i - l*640;
            float v = (n < 256) ? bv[l*256+n]
                    : (n < 512) ? bso[l*256+(n-256)]
                                : ba[l*128+(n-512)];
            bp[l*640+n] = v;
        }
    }
}

// ---------------------------------------------------------------- prep (src transpose)
__device__ __forceinline__ void tile_decode(int st, int& lvl, int& s0, int& hw, int& start)
{
    if (st < 256)      { lvl=0; s0=st*64;       hw=16384; start=0; }
    else if (st < 320) { lvl=1; s0=(st-256)*64; hw=4096;  start=16384; }
    else if (st < 336) { lvl=2; s0=(st-320)*64; hw=1024;  start=20480; }
    else               { lvl=3; s0=(st-336)*64; hw=256;   start=21504; }
}

__global__ __launch_bounds__(256) void prep_pos_kernel(
    const float* __restrict__ p0, const float* __restrict__ p1,
    const float* __restrict__ p2, const float* __restrict__ p3,
    const float* __restrict__ le, bf16* __restrict__ qpos)
{
    __shared__ float tile[32][65];
    int lvl, s0, hw, start; tile_decode(blockIdx.x, lvl, s0, hw, start);
    const float* sp = lvl==0?p0 : lvl==1?p1 : lvl==2?p2 : p3;
    const int t = threadIdx.x, b = blockIdx.z, c0 = blockIdx.y*32;
#pragma unroll
    for (int j=0;j<8;++j){
        int cl = j*4 + (t>>6), sl = t&63;
        tile[cl][sl] = sp[((size_t)b*256 + c0+cl)*hw + s0 + sl];
    }
    __syncthreads();
#pragma unroll
    for (int j=0;j<8;++j){
        int sl = j*8 + (t>>5), cl = t&31;
        float v = tile[cl][sl] + le[lvl*256 + c0 + cl];
        size_t o = ((size_t)b*N_TOK + start + s0 + sl)*256 + c0 + cl;
        qpos[o] = __float2bfloat16(v);
    }
}

__global__ __launch_bounds__(256) void prep_q_kernel(
    const float* __restrict__ s0p, const float* __restrict__ s1p,
    const float* __restrict__ s2p, const float* __restrict__ s3p,
    const bf16* __restrict__ qpos,
    bf16* __restrict__ qb, bf16* __restrict__ qpb)
{
    __shared__ float tile[32][65];
    int lvl, s0, hw, start; tile_decode(blockIdx.x, lvl, s0, hw, start);
    const float* sp = lvl==0?s0p : lvl==1?s1p : lvl==2?s2p : s3p;
    const int t = threadIdx.x, b = blockIdx.z, c0 = blockIdx.y*32;
#pragma unroll
    for (int j=0;j<8;++j){
        int cl = j*4 + (t>>6), sl = t&63;
        tile[cl][sl] = sp[((size_t)b*256 + c0+cl)*hw + s0 + sl];
    }
    __syncthreads();
#pragma unroll
    for (int j=0;j<8;++j){
        int sl = j*8 + (t>>5), cl = t&31;
        float v = tile[cl][sl];
        size_t o = ((size_t)b*N_TOK + start + s0 + sl)*256 + c0 + cl;
        qb[o] = __float2bfloat16(v);
        qpb[o] = __float2bfloat16(v + __bfloat162float(qpos[o]));
    }
}

// ---------------------------------------------------------------- GEMM (bf16 MFMA)
// C[M][N] = A[M][K](bf16) * Wt[N][K]^T(bf16) + bias, 128x128 tile, 4 waves 2x2.
// MODE 0: N=640 split -> value bf16 | off f32 | aw f32 (A2 for n>=256).
// MODE 1: bf16 out [M][256] (delta).
// MODE 2: relu -> bf16 out [M][1024].
template<int MODE>
__global__ __launch_bounds__(256) void gemm_kernel(
    const bf16* __restrict__ A, const bf16* __restrict__ A2,
    const bf16* __restrict__ Wt, const float* __restrict__ bias,
    int K, void* __restrict__ out0, void* __restrict__ out1, void* __restrict__ out2)
{
    __shared__ __align__(1024) ushort As[128*32];
    __shared__ __align__(1024) ushort Bs[128*32];
    const int tid = threadIdx.x;
    const int lane = tid & 63, w = tid >> 6;
    const int wr = w >> 1, wc = w & 1;
    const int lr = lane & 15, lg = lane >> 4;
    const size_t m0 = (size_t)blockIdx.x * 128;
    const int n0 = blockIdx.y * 128;
    const bf16* Ause = (MODE == 0 && n0 >= 256) ? A2 : A;

    const int srow0 = (w<<5) + (lane>>2);
    const int sphys = (lane&3);

    f32x4 acc[4][4];
#pragma unroll
    for (int i=0;i<4;++i)
#pragma unroll
        for (int j=0;j<4;++j) acc[i][j] = (f32x4){0.f,0.f,0.f,0.f};

    for (int k0 = 0; k0 < K; k0 += 32) {
#pragma unroll
        for (int j=0;j<2;++j){
            int row  = srow0 + j*16;
            int slot = sphys ^ ((row>>1)&3);  // pre-swizzled global source
            gload_lds16(&Ause[(m0+row)*(size_t)K + k0 + slot*8], &As[row*32 + sphys*8]);
            gload_lds16(&Wt[(size_t)(n0+row)*K + k0 + slot*8],   &Bs[row*32 + sphys*8]);
        }
        asm volatile("s_waitcnt vmcnt(0)" ::: "memory");
        __syncthreads();
        bf16x8 av[4], bw[4];
#pragma unroll
        for (int i=0;i<4;++i){
            int ar = wr*64 + i*16 + lr;
            int br = wc*64 + i*16 + lr;
            av[i] = *(bf16x8*)&As[ar*32 + ((lg ^ ((ar>>1)&3))<<3)];
            bw[i] = *(bf16x8*)&Bs[br*32 + ((lg ^ ((br>>1)&3))<<3)];
        }
#pragma unroll
        for (int mi=0;mi<4;++mi)
#pragma unroll
            for (int ni=0;ni<4;++ni)
                acc[mi][ni] = __builtin_amdgcn_mfma_f32_16x16x32_bf16(av[mi], bw[ni], acc[mi][ni], 0,0,0);
        __syncthreads();
    }
#pragma unroll
    for (int mi=0;mi<4;++mi){
#pragma unroll
        for (int ni=0;ni<4;++ni){
            int gr0 = (int)m0 + wr*64 + mi*16 + lg*4;
            int gc  = n0 + wc*64 + ni*16 + lr;
            float bb = bias[gc];
#pragma unroll
            for (int r=0;r<4;++r){
                float y = acc[mi][ni][r] + bb;
                size_t row = (size_t)(gr0 + r);
                if (MODE == 0) {
                    if (gc < 256)      ((bf16*)out0)[row*256 + gc] = __float2bfloat16(y);
                    else if (gc < 512) ((float*)out1)[row*256 + (gc-256)] = y;
                    else               ((float*)out2)[row*128 + (gc-512)] = y;
                } else if (MODE == 1) {
                    ((bf16*)out0)[row*256 + gc] = __float2bfloat16(y);
                } else {
                    ((bf16*)out0)[row*1024 + gc] = __float2bfloat16(fmaxf(y, 0.f));
                }
            }
        }
    }
}

// ---------------------------------------------------------------- deformable sampling
__device__ __forceinline__ float bf16_lo(uint u){ return __uint_as_float(u << 16); }
__device__ __forceinline__ float bf16_hi(uint u){ return __uint_as_float(u & 0xffff0000u); }

__global__ __launch_bounds__(256) void sample_kernel(
    const bf16* __restrict__ value, const float* __restrict__ offb,
    const float* __restrict__ awb, bf16* __restrict__ sampled)
{
    __shared__ float off_s[4][264];   // 8 heads * 33
    __shared__ float w_s[4][136];     // 8 heads * 17
    const int wv = threadIdx.x >> 6, lane = threadIdx.x & 63;
    const int m = blockIdx.x*4 + wv;
    const int h = lane >> 3;

    {   // stage offsets with +1-word pad per head
        float4 o4 = *(const float4*)&offb[(size_t)m*256 + lane*4];
        int r = (lane*4) & 31;
        off_s[wv][h*33 + r]     = o4.x;
        off_s[wv][h*33 + r + 1] = o4.y;
        off_s[wv][h*33 + r + 2] = o4.z;
        off_s[wv][h*33 + r + 3] = o4.w;
    }
    // softmax: 2 logits/lane, head = 8-lane group
    float2 lgt = *(const float2*)&awb[(size_t)m*128 + lane*2];
    float mx = fmaxf(lgt.x, lgt.y);
#pragma unroll
    for (int o=1;o<8;o<<=1) mx = fmaxf(mx, __shfl_xor(mx, o));
    float e0 = __expf(lgt.x - mx), e1 = __expf(lgt.y - mx);
    float sm = e0 + e1;
#pragma unroll
    for (int o=1;o<8;o<<=1) sm += __shfl_xor(sm, o);
    float rs = __frcp_rn(sm);
    {
        int idx = (lane*2) & 15;
        w_s[wv][h*17 + idx]     = e0 * rs;
        w_s[wv][h*17 + idx + 1] = e1 * rs;
    }
    __syncthreads();

    const int b = m / N_TOK;
    const int n = m - b*N_TOK;
    float refx, refy;
    if (n < 16384)      { int s=n;       int qy=s>>7, qx=s&127; refx=(qx+0.5f)*(1.f/128.f); refy=(qy+0.5f)*(1.f/128.f); }
    else if (n < 20480) { int s=n-16384; int qy=s>>6, qx=s&63;  refx=(qx+0.5f)*(1.f/64.f);  refy=(qy+0.5f)*(1.f/64.f); }
    else if (n < 21504) { int s=n-20480; int qy=s>>5, qx=s&31;  refx=(qx+0.5f)*(1.f/32.f);  refy=(qy+0.5f)*(1.f/32.f); }
    else                { int s=n-21504; int qy=s>>4, qx=s&15;  refx=(qx+0.5f)*(1.f/16.f);  refy=(qy+0.5f)*(1.f/16.f); }

    const int c = lane & 7;           // channel-group (4 ch)
    const bf16* vb = value + (size_t)b*N_TOK*256 + h*32 + c*4;
    const int LSTART[4] = {0, 16384, 20480, 21504};
    f32x4 acc = (f32x4){0.f,0.f,0.f,0.f};
#pragma unroll
    for (int lvl=0; lvl<4; ++lvl){
        const int wl = 128 >> lvl;
        const bf16* base = vb + (size_t)LSTART[lvl]*256;
        const float bx = refx*(float)wl - 0.5f, by = refy*(float)wl - 0.5f;
#pragma unroll
        for (int p=0;p<4;++p){
            const int oi = h*33 + (lvl<<3) + (p<<1);
            float fx = bx + off_s[wv][oi];
            float fy = by + off_s[wv][oi+1];
            float wgt = w_s[wv][h*17 + (lvl<<2) + p];
            float x0f = floorf(fx), y0f = floorf(fy);
            float dx = fx - x0f, dy = fy - y0f;
            int ix = (int)x0f, iy = (int)y0f;
            int cx0 = min(max(ix,0),   wl-1), cx1 = min(max(ix+1,0), wl-1);
            int cy0 = min(max(iy,0),   wl-1), cy1 = min(max(iy+1,0), wl-1);
            bool vx0 = (unsigned)ix     < (unsigned)wl, vx1 = (unsigned)(ix+1) < (unsigned)wl;
            bool vy0 = (unsigned)iy     < (unsigned)wl, vy1 = (unsigned)(iy+1) < (unsigned)wl;
            float w00 = (vx0&&vy0) ? (1.f-dx)*(1.f-dy)*wgt : 0.f;
            float w01 = (vx1&&vy0) ? dx*(1.f-dy)*wgt       : 0.f;
            float w10 = (vx0&&vy1) ? (1.f-dx)*dy*wgt       : 0.f;
            float w11 = (vx1&&vy1) ? dx*dy*wgt             : 0.f;
            uint2 q00 = *(const uint2*)&base[(size_t)(cy0*wl+cx0)*256];
            uint2 q01 = *(const uint2*)&base[(size_t)(cy0*wl+cx1)*256];
            uint2 q10 = *(const uint2*)&base[(size_t)(cy1*wl+cx0)*256];
            uint2 q11 = *(const uint2*)&base[(size_t)(cy1*wl+cx1)*256];
            acc[0] += w00*bf16_lo(q00.x) + w01*bf16_lo(q01.x) + w10*bf16_lo(q10.x) + w11*bf16_lo(q11.x);
            acc[1] += w00*bf16_hi(q00.x) + w01*bf16_hi(q01.x) + w10*bf16_hi(q10.x) + w11*bf16_hi(q11.x);
            acc[2] += w00*bf16_lo(q00.y) + w01*bf16_lo(q01.y) + w10*bf16_lo(q10.y) + w11*bf16_lo(q11.y);
            acc[3] += w00*bf16_hi(q00.y) + w01*bf16_hi(q01.y) + w10*bf16_hi(q10.y) + w11*bf16_hi(q11.y);
        }
    }
    ushort4 outv;
    outv.x = f2b(acc[0]);
    outv.y = f2b(acc[1]);
    outv.z = f2b(acc[2]);
    outv.w = f2b(acc[3]);
    *(ushort4*)&sampled[(size_t)m*256 + h*32 + c*4] = outv;
}

// ---------------------------------------------------------------- residual + LN
// One wave per token (4 tokens/block), bf16 streams: x = qb + delta; y = LN(x).
// Writes qb (the q stream), qpb = bf16(y + qpos); optional f32 dout (last layer).
__global__ __launch_bounds__(256) void ln_kernel(
    bf16* __restrict__ qb, const bf16* __restrict__ delta,
    const float* __restrict__ g, const float* __restrict__ be,
    const bf16* __restrict__ qpos, bf16* __restrict__ qpb, float* __restrict__ dout)
{
    const int wv = threadIdx.x >> 6, lane = threadIdx.x & 63;
    const size_t o = ((size_t)blockIdx.x*4 + wv)*256 + lane*4;
    ushort4 qv = *(const ushort4*)&qb[o];
    ushort4 dv = *(const ushort4*)&delta[o];
    float x0 = bfu(qv.x) + bfu(dv.x);
    float x1 = bfu(qv.y) + bfu(dv.y);
    float x2 = bfu(qv.z) + bfu(dv.z);
    float x3 = bfu(qv.w) + bfu(dv.w);
    float s1 = x0+x1+x2+x3;
    float s2 = x0*x0+x1*x1+x2*x2+x3*x3;
#pragma unroll
    for (int i=1;i<64;i<<=1){ s1 += __shfl_xor(s1,i); s2 += __shfl_xor(s2,i); }
    float mu  = s1 * (1.f/256.f);
    float var = s2 * (1.f/256.f) - mu*mu;
    float rs  = rsqrtf(var + 1e-5f);
    float4 gv = *(const float4*)&g[lane*4];
    float4 bv = *(const float4*)&be[lane*4];
    float y0 = (x0-mu)*rs*gv.x + bv.x;
    float y1 = (x1-mu)*rs*gv.y + bv.y;
    float y2 = (x2-mu)*rs*gv.z + bv.z;
    float y3 = (x3-mu)*rs*gv.w + bv.w;
    ushort4 qo; qo.x=f2b(y0); qo.y=f2b(y1); qo.z=f2b(y2); qo.w=f2b(y3);
    *(ushort4*)&qb[o] = qo;
    ushort4 pv = *(const ushort4*)&qpos[o];
    ushort4 po;
    po.x = f2b(y0 + bfu(pv.x));
    po.y = f2b(y1 + bfu(pv.y));
    po.z = f2b(y2 + bfu(pv.z));
    po.w = f2b(y3 + bfu(pv.w));
    *(ushort4*)&qpb[o] = po;
    if (dout) { *(float4*)&dout[o] = make_float4(y0,y1,y2,y3); }
}

// ---------------------------------------------------------------- launch
extern "C" void kernel_launch(void* const* d_in, const int* in_sizes, int n_in,
                              void* d_out, int out_size, void* d_ws, size_t ws_size,
                              hipStream_t stream)
{
    // setup_inputs() dict order is INTERLEAVED: src0,pos0,src1,pos1,...
    const float* src0 = (const float*)d_in[0];
    const float* pos0 = (const float*)d_in[1];
    const float* src1 = (const float*)d_in[2];
    const float* pos1 = (const float*)d_in[3];
    const float* src2 = (const float*)d_in[4];
    const float* pos2 = (const float*)d_in[5];
    const float* src3 = (const float*)d_in[6];
    const float* pos3 = (const float*)d_in[7];
    const float* le   = (const float*)d_in[8];
    const float* Wv   = (const float*)d_in[9];
    const float* bv   = (const float*)d_in[10];
    const float* Ws   = (const float*)d_in[11];
    const float* bso  = (const float*)d_in[12];
    const float* Wa   = (const float*)d_in[13];
    const float* ba   = (const float*)d_in[14];
    const float* Wo   = (const float*)d_in[15];
    const float* bo   = (const float*)d_in[16];
    const float* g1   = (const float*)d_in[17];
    const float* be1  = (const float*)d_in[18];
    const float* W1   = (const float*)d_in[19];
    const float* b1   = (const float*)d_in[20];
    const float* W2   = (const float*)d_in[21];
    const float* b2   = (const float*)d_in[22];
    const float* g2   = (const float*)d_in[23];
    const float* be2  = (const float*)d_in[24];

    if (ws_size < WS_NEED) {   // diagnostic: absmax ~1e6 means ws too small
        sentinel_kernel<<<1, 1, 0, stream>>>((float*)d_out);
        return;
    }
    char* ws = (char*)d_ws;
    bf16*  qpos   = (bf16*) (ws + OFF_QPOS);
    bf16*  qb     = (bf16*) (ws + OFF_QB);
    bf16*  qpb    = (bf16*) (ws + OFF_QPB);
    bf16*  sampled= (bf16*) (ws + OFF_QPB);   // alias: qpb dead gemm0->ln1
    bf16*  wp     = (bf16*) (ws + OFF_WP);
    float* bp     = (float*)(ws + OFF_BP);
    float* offb   = (float*)(ws + OFF_R1);    // gemm0 -> sample
    bf16*  hidden = (bf16*) (ws + OFF_R1);    // gemm2 -> gemm3 chunk (disjoint lifetime)
    bf16*  value  = (bf16*) (ws + OFF_VAL);   // gemm0 -> sample
    bf16*  delta  = (bf16*) (ws + OFF_VAL);   // gemm1/3 -> ln (value dead by then)
    float* awb    = (float*)(ws + OFF_AW);

    pack_kernel<<<dim3(4096), 256, 0, stream>>>(Wv, Ws, Wa, Wo, W1, W2, bv, bso, ba, wp, bp);
    prep_pos_kernel<<<dim3(340,8,2), 256, 0, stream>>>(pos0,pos1,pos2,pos3, le, qpos);
    prep_q_kernel<<<dim3(340,8,2), 256, 0, stream>>>(src0,src1,src2,src3, qpos, qb, qpb);

    for (int l = 0; l < NLAY; ++l) {
        const bf16* wl_ = wp + (size_t)l*PER_L;
        gemm_kernel<0><<<dim3(340,5), 256, 0, stream>>>(qb, qpb, wl_, bp + l*640, 256,
                                                        value, offb, awb);
        sample_kernel<<<dim3(M_TOT/4), 256, 0, stream>>>(value, offb, awb, sampled);
        gemm_kernel<1><<<dim3(340,2), 256, 0, stream>>>(sampled, nullptr, wl_ + WVSA_SZ,
                                                        bo + l*256, 256, delta, nullptr, nullptr);
        ln_kernel<<<dim3(M_TOT/4), 256, 0, stream>>>(qb, delta, g1 + l*256, be1 + l*256,
                                                     qpos, qpb, nullptr);
        // FFN, chunked x2 so hidden (44.56 MB) aliases the dead offb region
        for (int c = 0; c < 2; ++c) {
            const size_t mo = (size_t)c * (M_TOT/2);
            gemm_kernel<2><<<dim3(170,8), 256, 0, stream>>>(qb + mo*256, nullptr,
                                                            wl_ + WVSA_SZ + WO_SZ,
                                                            b1 + l*1024, 256, hidden, nullptr, nullptr);
            gemm_kernel<1><<<dim3(170,2), 256, 0, stream>>>(hidden, nullptr,
                                                            wl_ + WVSA_SZ + WO_SZ + W1_SZ,
                                                            b2 + l*256, 1024, delta + mo*256, nullptr, nullptr);
        }
        ln_kernel<<<dim3(M_TOT/4), 256, 0, stream>>>(qb, delta, g2 + l*256, be2 + l*256,
                                                     qpos, qpb, (l==NLAY-1) ? (float*)d_out : nullptr);
    }
}

// Round 8
// 1842.691 us; speedup vs baseline: 1.9130x; 1.0282x over previous
//
#include <hip/hip_runtime.h>
#include <hip/hip_bf16.h>
#include <stdint.h>

#define D_MODEL 256
#define N_TOK   21760
#define BATCH   2
#define M_TOT   (BATCH*N_TOK)   // 43520 = 340*128
#define NLAY    6

typedef __hip_bfloat16 bf16;
typedef short bf16x8 __attribute__((ext_vector_type(8)));
typedef float f32x4  __attribute__((ext_vector_type(4)));

// packed per-layer weight block (bf16, transposed to [N][K])
#define WVSA_SZ (640*256)
#define WO_SZ   (256*256)
#define W1_SZ   (1024*256)
#define W2_SZ   (256*1024)
#define PER_L   (WVSA_SZ+WO_SZ+W1_SZ+W2_SZ)  // 753664

// ---- workspace layout (aliased by lifetime), total ~165.4 MB ----
#define SZ_QF   ((size_t)M_TOT*256*4)   // offb f32 / hidden chunk
#define SZ_BF   ((size_t)M_TOT*256*2)
#define SZ_AW   ((size_t)M_TOT*128*4)
#define SZ_WP   ((size_t)PER_L*NLAY*2)
#define SZ_BP   ((size_t)NLAY*640*4)
#define OFF_QPOS  ((size_t)0)
#define OFF_QB    (OFF_QPOS + SZ_BF)
#define OFF_QPB   (OFF_QB   + SZ_BF)    // also `sampled`
#define OFF_WP    (OFF_QPB  + SZ_BF)
#define OFF_BP    (OFF_WP   + SZ_WP)
#define OFF_R1    (OFF_BP   + SZ_BP)    // offb f32 | hidden chunk (44.56 MB)
#define OFF_VAL   (OFF_R1   + SZ_QF)    // value bf16 | delta bf16 (22.28 MB)
#define OFF_AW    (OFF_VAL  + SZ_BF)
#define WS_NEED   (OFF_AW   + SZ_AW)

// ---------------------------------------------------------------- helpers
typedef const __attribute__((address_space(1))) void gvoid_t;
typedef __attribute__((address_space(3))) void lvoid_t;
__device__ __forceinline__ void gload_lds16(const void* g, void* l){
    __builtin_amdgcn_global_load_lds((gvoid_t*)g, (lvoid_t*)l, 16, 0, 0);
}
__device__ __forceinline__ float bfu(ushort u){ return __uint_as_float(((uint)u)<<16); }
__device__ __forceinline__ ushort f2b(float f){ return __bfloat16_as_ushort(__float2bfloat16(f)); }
__device__ __forceinline__ float bf16_lo(uint u){ return __uint_as_float(u << 16); }
__device__ __forceinline__ float bf16_hi(uint u){ return __uint_as_float(u & 0xffff0000u); }

// ---------------------------------------------------------------- sentinel
__global__ void sentinel_kernel(float* out) { out[0] = 1.0e6f; }

// ---------------------------------------------------------------- pack
__global__ void pack_kernel(const float* __restrict__ Wv, const float* __restrict__ Ws,
                            const float* __restrict__ Wa, const float* __restrict__ Wo,
                            const float* __restrict__ W1, const float* __restrict__ W2,
                            const float* __restrict__ bv, const float* __restrict__ bso,
                            const float* __restrict__ ba,
                            bf16* __restrict__ wp, float* __restrict__ bp)
{
    const int WTOT = PER_L * NLAY;
    for (int idx = blockIdx.x*blockDim.x + threadIdx.x; idx < WTOT + NLAY*640;
         idx += gridDim.x*blockDim.x) {
        if (idx < WTOT) {
            int l = idx / PER_L, r = idx - l*PER_L;
            float v;
            if (r < WVSA_SZ) {                       // Wvsa_t[640][256]
                int n = r >> 8, k = r & 255;
                if (n < 256)      v = Wv[((size_t)l*256+k)*256 + n];
                else if (n < 512) v = Ws[((size_t)l*256+k)*256 + (n-256)];
                else              v = Wa[((size_t)l*256+k)*128 + (n-512)];
            } else if (r < WVSA_SZ+WO_SZ) {          // Wo_t[256][256]
                int j = r - WVSA_SZ; int n = j >> 8, k = j & 255;
                v = Wo[((size_t)l*256+k)*256 + n];
            } else if (r < WVSA_SZ+WO_SZ+W1_SZ) {    // W1_t[1024][256]
                int j = r - (WVSA_SZ+WO_SZ); int n = j >> 8, k = j & 255;
                v = W1[((size_t)l*256+k)*1024 + n];
            } else {                                 // W2_t[256][1024]
                int j = r - (WVSA_SZ+WO_SZ+W1_SZ); int n = j >> 10, k = j & 1023;
                v = W2[((size_t)l*1024+k)*256 + n];
            }
            wp[idx] = __float2bfloat16(v);
        } else {
            int i = idx - WTOT; int l = i / 640, n = i - l*640;
            float v = (n < 256) ? bv[l*256+n]
                    : (n < 512) ? bso[l*256+(n-256)]
                                : ba[l*128+(n-512)];
            bp[l*640+n] = v;
        }
    }
}

// ---------------------------------------------------------------- prep (src transpose)
__device__ __forceinline__ void tile_decode(int st, int& lvl, int& s0, int& hw, int& start)
{
    if (st < 256)      { lvl=0; s0=st*64;       hw=16384; start=0; }
    else if (st < 320) { lvl=1; s0=(st-256)*64; hw=4096;  start=16384; }
    else if (st < 336) { lvl=2; s0=(st-320)*64; hw=1024;  start=20480; }
    else               { lvl=3; s0=(st-336)*64; hw=256;   start=21504; }
}

__global__ __launch_bounds__(256) void prep_pos_kernel(
    const float* __restrict__ p0, const float* __restrict__ p1,
    const float* __restrict__ p2, const float* __restrict__ p3,
    const float* __restrict__ le, bf16* __restrict__ qpos)
{
    __shared__ float tile[32][65];
    int lvl, s0, hw, start; tile_decode(blockIdx.x, lvl, s0, hw, start);
    const float* sp = lvl==0?p0 : lvl==1?p1 : lvl==2?p2 : p3;
    const int t = threadIdx.x, b = blockIdx.z, c0 = blockIdx.y*32;
#pragma unroll
    for (int j=0;j<8;++j){
        int cl = j*4 + (t>>6), sl = t&63;
        tile[cl][sl] = sp[((size_t)b*256 + c0+cl)*hw + s0 + sl];
    }
    __syncthreads();
#pragma unroll
    for (int j=0;j<8;++j){
        int sl = j*8 + (t>>5), cl = t&31;
        float v = tile[cl][sl] + le[lvl*256 + c0 + cl];
        size_t o = ((size_t)b*N_TOK + start + s0 + sl)*256 + c0 + cl;
        qpos[o] = __float2bfloat16(v);
    }
}

__global__ __launch_bounds__(256) void prep_q_kernel(
    const float* __restrict__ s0p, const float* __restrict__ s1p,
    const float* __restrict__ s2p, const float* __restrict__ s3p,
    const bf16* __restrict__ qpos,
    bf16* __restrict__ qb, bf16* __restrict__ qpb)
{
    __shared__ float tile[32][65];
    int lvl, s0, hw, start; tile_decode(blockIdx.x, lvl, s0, hw, start);
    const float* sp = lvl==0?s0p : lvl==1?s1p : lvl==2?s2p : s3p;
    const int t = threadIdx.x, b = blockIdx.z, c0 = blockIdx.y*32;
#pragma unroll
    for (int j=0;j<8;++j){
        int cl = j*4 + (t>>6), sl = t&63;
        tile[cl][sl] = sp[((size_t)b*256 + c0+cl)*hw + s0 + sl];
    }
    __syncthreads();
#pragma unroll
    for (int j=0;j<8;++j){
        int sl = j*8 + (t>>5), cl = t&31;
        float v = tile[cl][sl];
        size_t o = ((size_t)b*N_TOK + start + s0 + sl)*256 + c0 + cl;
        qb[o] = __float2bfloat16(v);
        qpb[o] = __float2bfloat16(v + __bfloat162float(qpos[o]));
    }
}

// ---------------------------------------------------------------- GEMM (bf16 MFMA)
template<int MODE>
__global__ __launch_bounds__(256) void gemm_kernel(
    const bf16* __restrict__ A, const bf16* __restrict__ A2,
    const bf16* __restrict__ Wt, const float* __restrict__ bias,
    int K, void* __restrict__ out0, void* __restrict__ out1, void* __restrict__ out2)
{
    __shared__ __align__(1024) ushort As[128*32];
    __shared__ __align__(1024) ushort Bs[128*32];
    const int tid = threadIdx.x;
    const int lane = tid & 63, w = tid >> 6;
    const int wr = w >> 1, wc = w & 1;
    const int lr = lane & 15, lg = lane >> 4;
    const size_t m0 = (size_t)blockIdx.x * 128;
    const int n0 = blockIdx.y * 128;
    const bf16* Ause = (MODE == 0 && n0 >= 256) ? A2 : A;

    const int srow0 = (w<<5) + (lane>>2);
    const int sphys = (lane&3);

    f32x4 acc[4][4];
#pragma unroll
    for (int i=0;i<4;++i)
#pragma unroll
        for (int j=0;j<4;++j) acc[i][j] = (f32x4){0.f,0.f,0.f,0.f};

    for (int k0 = 0; k0 < K; k0 += 32) {
#pragma unroll
        for (int j=0;j<2;++j){
            int row  = srow0 + j*16;
            int slot = sphys ^ ((row>>1)&3);  // pre-swizzled global source
            gload_lds16(&Ause[(m0+row)*(size_t)K + k0 + slot*8], &As[row*32 + sphys*8]);
            gload_lds16(&Wt[(size_t)(n0+row)*K + k0 + slot*8],   &Bs[row*32 + sphys*8]);
        }
        asm volatile("s_waitcnt vmcnt(0)" ::: "memory");
        __syncthreads();
        bf16x8 av[4], bw[4];
#pragma unroll
        for (int i=0;i<4;++i){
            int ar = wr*64 + i*16 + lr;
            int br = wc*64 + i*16 + lr;
            av[i] = *(bf16x8*)&As[ar*32 + ((lg ^ ((ar>>1)&3))<<3)];
            bw[i] = *(bf16x8*)&Bs[br*32 + ((lg ^ ((br>>1)&3))<<3)];
        }
#pragma unroll
        for (int mi=0;mi<4;++mi)
#pragma unroll
            for (int ni=0;ni<4;++ni)
                acc[mi][ni] = __builtin_amdgcn_mfma_f32_16x16x32_bf16(av[mi], bw[ni], acc[mi][ni], 0,0,0);
        __syncthreads();
    }
#pragma unroll
    for (int mi=0;mi<4;++mi){
#pragma unroll
        for (int ni=0;ni<4;++ni){
            int gr0 = (int)m0 + wr*64 + mi*16 + lg*4;
            int gc  = n0 + wc*64 + ni*16 + lr;
            float bb = bias[gc];
#pragma unroll
            for (int r=0;r<4;++r){
                float y = acc[mi][ni][r] + bb;
                size_t row = (size_t)(gr0 + r);
                if (MODE == 0) {
                    if (gc < 256)      ((bf16*)out0)[row*256 + gc] = __float2bfloat16(y);
                    else if (gc < 512) ((float*)out1)[row*256 + (gc-256)] = y;
                    else               ((float*)out2)[row*128 + (gc-512)] = y;
                } else if (MODE == 1) {
                    ((bf16*)out0)[row*256 + gc] = __float2bfloat16(y);
                } else {
                    ((bf16*)out0)[row*1024 + gc] = __float2bfloat16(fmaxf(y, 0.f));
                }
            }
        }
    }
}

// ---------------------------------------------------------------- deformable sampling
// One wave per token. Phase 1: each lane computes weights+byte-offsets for 2 of
// the 128 (h,lvl,p) points into an LDS table (head-padded x17 slots: distinct
// bank clusters per head-group on the b128 broadcast reads). Phase 2: each lane
// (h = lane>>3, c = lane&7) does pure table-driven gather+FMA for 4 channels.
__global__ __launch_bounds__(256) void sample_kernel(
    const bf16* __restrict__ value, const float* __restrict__ offb,
    const float* __restrict__ awb, bf16* __restrict__ sampled)
{
    __shared__ float tabw[4][136][4];   // 8 heads * 17 slots
    __shared__ int   tabo[4][136][4];
    const int wv = threadIdx.x >> 6, lane = threadIdx.x & 63;
    const int m = blockIdx.x*4 + wv;

    const int b = m / N_TOK;
    const int n = m - b*N_TOK;
    float refx, refy;
    if (n < 16384)      { int s=n;       int qy=s>>7, qx=s&127; refx=(qx+0.5f)*(1.f/128.f); refy=(qy+0.5f)*(1.f/128.f); }
    else if (n < 20480) { int s=n-16384; int qy=s>>6, qx=s&63;  refx=(qx+0.5f)*(1.f/64.f);  refy=(qy+0.5f)*(1.f/64.f); }
    else if (n < 21504) { int s=n-20480; int qy=s>>5, qx=s&31;  refx=(qx+0.5f)*(1.f/32.f);  refy=(qy+0.5f)*(1.f/32.f); }
    else                { int s=n-21504; int qy=s>>4, qx=s&15;  refx=(qx+0.5f)*(1.f/16.f);  refy=(qy+0.5f)*(1.f/16.f); }

    // softmax: 2 logits/lane == this lane's 2 phase-1 points; head = 8-lane group
    float2 lgt = *(const float2*)&awb[(size_t)m*128 + lane*2];
    float mx = fmaxf(lgt.x, lgt.y);
#pragma unroll
    for (int o=1;o<8;o<<=1) mx = fmaxf(mx, __shfl_xor(mx, o));
    float e0 = __expf(lgt.x - mx), e1 = __expf(lgt.y - mx);
    float sm = e0 + e1;
#pragma unroll
    for (int o=1;o<8;o<<=1) sm += __shfl_xor(sm, o);
    float rs = __frcp_rn(sm);
    float wgt0 = e0 * rs, wgt1 = e1 * rs;

    // offsets for points 2*lane, 2*lane+1
    float4 o4 = *(const float4*)&offb[(size_t)m*256 + lane*4];

    const int LSTART[4] = {0, 16384, 20480, 21504};
#pragma unroll
    for (int j=0;j<2;++j){
        int pg  = lane*2 + j;
        int lvl = (pg >> 2) & 3;
        int wl  = 128 >> lvl;
        float offx = j ? o4.z : o4.x;
        float offy = j ? o4.w : o4.y;
        float wgt  = j ? wgt1 : wgt0;
        float fx = refx*(float)wl - 0.5f + offx;
        float fy = refy*(float)wl - 0.5f + offy;
        float x0f = floorf(fx), y0f = floorf(fy);
        float dx = fx - x0f, dy = fy - y0f;
        int ix = (int)x0f, iy = (int)y0f;
        int cx0 = min(max(ix,0),   wl-1), cx1 = min(max(ix+1,0), wl-1);
        int cy0 = min(max(iy,0),   wl-1), cy1 = min(max(iy+1,0), wl-1);
        bool vx0 = (unsigned)ix     < (unsigned)wl, vx1 = (unsigned)(ix+1) < (unsigned)wl;
        bool vy0 = (unsigned)iy     < (unsigned)wl, vy1 = (unsigned)(iy+1) < (unsigned)wl;
        float a = 1.f-dx, bb = 1.f-dy;
        int slot = (pg >> 4)*17 + (pg & 15);
        float4 wq;
        wq.x = (vx0&&vy0) ? a*bb*wgt : 0.f;
        wq.y = (vx1&&vy0) ? dx*bb*wgt : 0.f;
        wq.z = (vx0&&vy1) ? a*dy*wgt : 0.f;
        wq.w = (vx1&&vy1) ? dx*dy*wgt : 0.f;
        *(float4*)&tabw[wv][slot][0] = wq;
        int lb = LSTART[lvl];
        int4 oq;
        oq.x = (lb + cy0*wl + cx0) << 9;
        oq.y = (lb + cy0*wl + cx1) << 9;
        oq.z = (lb + cy1*wl + cx0) << 9;
        oq.w = (lb + cy1*wl + cx1) << 9;
        *(int4*)&tabo[wv][slot][0] = oq;
    }
    __syncthreads();

    const int h = lane >> 3, c = lane & 7;
    const int rb = __builtin_amdgcn_readfirstlane(b);   // SGPR base -> s-base+voffset loads
    const char* vb = (const char*)value + (size_t)rb*N_TOK*512;
    const int laneoff = (h*32 + c*4)*2;
    f32x4 acc = (f32x4){0.f,0.f,0.f,0.f};
#pragma unroll 4
    for (int k=0;k<16;++k){
        int slot = h*17 + k;
        float4 w  = *(const float4*)&tabw[wv][slot][0];
        int4   io = *(const int4*)  &tabo[wv][slot][0];
        uint2 q00 = *(const uint2*)(vb + (io.x + laneoff));
        uint2 q01 = *(const uint2*)(vb + (io.y + laneoff));
        uint2 q10 = *(const uint2*)(vb + (io.z + laneoff));
        uint2 q11 = *(const uint2*)(vb + (io.w + laneoff));
        acc[0] += w.x*bf16_lo(q00.x) + w.y*bf16_lo(q01.x) + w.z*bf16_lo(q10.x) + w.w*bf16_lo(q11.x);
        acc[1] += w.x*bf16_hi(q00.x) + w.y*bf16_hi(q01.x) + w.z*bf16_hi(q10.x) + w.w*bf16_hi(q11.x);
        acc[2] += w.x*bf16_lo(q00.y) + w.y*bf16_lo(q01.y) + w.z*bf16_lo(q10.y) + w.w*bf16_lo(q11.y);
        acc[3] += w.x*bf16_hi(q00.y) + w.y*bf16_hi(q01.y) + w.z*bf16_hi(q10.y) + w.w*bf16_hi(q11.y);
    }
    ushort4 outv;
    outv.x = f2b(acc[0]);
    outv.y = f2b(acc[1]);
    outv.z = f2b(acc[2]);
    outv.w = f2b(acc[3]);
    *(ushort4*)&sampled[(size_t)m*256 + h*32 + c*4] = outv;
}

// ---------------------------------------------------------------- residual + LN
__global__ __launch_bounds__(256) void ln_kernel(
    bf16* __restrict__ qb, const bf16* __restrict__ delta,
    const float* __restrict__ g, const float* __restrict__ be,
    const bf16* __restrict__ qpos, bf16* __restrict__ qpb, float* __restrict__ dout)
{
    const int wv = threadIdx.x >> 6, lane = threadIdx.x & 63;
    const size_t o = ((size_t)blockIdx.x*4 + wv)*256 + lane*4;
    ushort4 qv = *(const ushort4*)&qb[o];
    ushort4 dv = *(const ushort4*)&delta[o];
    float x0 = bfu(qv.x) + bfu(dv.x);
    float x1 = bfu(qv.y) + bfu(dv.y);
    float x2 = bfu(qv.z) + bfu(dv.z);
    float x3 = bfu(qv.w) + bfu(dv.w);
    float s1 = x0+x1+x2+x3;
    float s2 = x0*x0+x1*x1+x2*x2+x3*x3;
#pragma unroll
    for (int i=1;i<64;i<<=1){ s1 += __shfl_xor(s1,i); s2 += __shfl_xor(s2,i); }
    float mu  = s1 * (1.f/256.f);
    float var = s2 * (1.f/256.f) - mu*mu;
    float rs  = rsqrtf(var + 1e-5f);
    float4 gv = *(const float4*)&g[lane*4];
    float4 bv = *(const float4*)&be[lane*4];
    float y0 = (x0-mu)*rs*gv.x + bv.x;
    float y1 = (x1-mu)*rs*gv.y + bv.y;
    float y2 = (x2-mu)*rs*gv.z + bv.z;
    float y3 = (x3-mu)*rs*gv.w + bv.w;
    ushort4 qo; qo.x=f2b(y0); qo.y=f2b(y1); qo.z=f2b(y2); qo.w=f2b(y3);
    *(ushort4*)&qb[o] = qo;
    ushort4 pv = *(const ushort4*)&qpos[o];
    ushort4 po;
    po.x = f2b(y0 + bfu(pv.x));
    po.y = f2b(y1 + bfu(pv.y));
    po.z = f2b(y2 + bfu(pv.z));
    po.w = f2b(y3 + bfu(pv.w));
    *(ushort4*)&qpb[o] = po;
    if (dout) { *(float4*)&dout[o] = make_float4(y0,y1,y2,y3); }
}

// ---------------------------------------------------------------- launch
extern "C" void kernel_launch(void* const* d_in, const int* in_sizes, int n_in,
                              void* d_out, int out_size, void* d_ws, size_t ws_size,
                              hipStream_t stream)
{
    // setup_inputs() dict order is INTERLEAVED: src0,pos0,src1,pos1,...
    const float* src0 = (const float*)d_in[0];
    const float* pos0 = (const float*)d_in[1];
    const float* src1 = (const float*)d_in[2];
    const float* pos1 = (const float*)d_in[3];
    const float* src2 = (const float*)d_in[4];
    const float* pos2 = (const float*)d_in[5];
    const float* src3 = (const float*)d_in[6];
    const float* pos3 = (const float*)d_in[7];
    const float* le   = (const float*)d_in[8];
    const float* Wv   = (const float*)d_in[9];
    const float* bv   = (const float*)d_in[10];
    const float* Ws   = (const float*)d_in[11];
    const float* bso  = (const float*)d_in[12];
    const float* Wa   = (const float*)d_in[13];
    const float* ba   = (const float*)d_in[14];
    const float* Wo   = (const float*)d_in[15];
    const float* bo   = (const float*)d_in[16];
    const float* g1   = (const float*)d_in[17];
    const float* be1  = (const float*)d_in[18];
    const float* W1   = (const float*)d_in[19];
    const float* b1   = (const float*)d_in[20];
    const float* W2   = (const float*)d_in[21];
    const float* b2   = (const float*)d_in[22];
    const float* g2   = (const float*)d_in[23];
    const float* be2  = (const float*)d_in[24];

    if (ws_size < WS_NEED) {   // diagnostic: absmax ~1e6 means ws too small
        sentinel_kernel<<<1, 1, 0, stream>>>((float*)d_out);
        return;
    }
    char* ws = (char*)d_ws;
    bf16*  qpos   = (bf16*) (ws + OFF_QPOS);
    bf16*  qb     = (bf16*) (ws + OFF_QB);
    bf16*  qpb    = (bf16*) (ws + OFF_QPB);
    bf16*  sampled= (bf16*) (ws + OFF_QPB);   // alias: qpb dead gemm0->ln1
    bf16*  wp     = (bf16*) (ws + OFF_WP);
    float* bp     = (float*)(ws + OFF_BP);
    float* offb   = (float*)(ws + OFF_R1);    // gemm0 -> sample
    bf16*  hidden = (bf16*) (ws + OFF_R1);    // gemm2 -> gemm3 chunk (disjoint lifetime)
    bf16*  value  = (bf16*) (ws + OFF_VAL);   // gemm0 -> sample
    bf16*  delta  = (bf16*) (ws + OFF_VAL);   // gemm1/3 -> ln (value dead by then)
    float* awb    = (float*)(ws + OFF_AW);

    pack_kernel<<<dim3(4096), 256, 0, stream>>>(Wv, Ws, Wa, Wo, W1, W2, bv, bso, ba, wp, bp);
    prep_pos_kernel<<<dim3(340,8,2), 256, 0, stream>>>(pos0,pos1,pos2,pos3, le, qpos);
    prep_q_kernel<<<dim3(340,8,2), 256, 0, stream>>>(src0,src1,src2,src3, qpos, qb, qpb);

    for (int l = 0; l < NLAY; ++l) {
        const bf16* wl_ = wp + (size_t)l*PER_L;
        gemm_kernel<0><<<dim3(340,5), 256, 0, stream>>>(qb, qpb, wl_, bp + l*640, 256,
                                                        value, offb, awb);
        sample_kernel<<<dim3(M_TOT/4), 256, 0, stream>>>(value, offb, awb, sampled);
        gemm_kernel<1><<<dim3(340,2), 256, 0, stream>>>(sampled, nullptr, wl_ + WVSA_SZ,
                                                        bo + l*256, 256, delta, nullptr, nullptr);
        ln_kernel<<<dim3(M_TOT/4), 256, 0, stream>>>(qb, delta, g1 + l*256, be1 + l*256,
                                                     qpos, qpb, nullptr);
        // FFN, chunked x2 so hidden (44.56 MB) aliases the dead offb region
        for (int c = 0; c < 2; ++c) {
            const size_t mo = (size_t)c * (M_TOT/2);
            gemm_kernel<2><<<dim3(170,8), 256, 0, stream>>>(qb + mo*256, nullptr,
                                                            wl_ + WVSA_SZ + WO_SZ,
                                                            b1 + l*1024, 256, hidden, nullptr, nullptr);
            gemm_kernel<1><<<dim3(170,2), 256, 0, stream>>>(hidden, nullptr,
                                                            wl_ + WVSA_SZ + WO_SZ + W1_SZ,
                                                            b2 + l*256, 1024, delta + mo*256, nullptr, nullptr);
        }
        ln_kernel<<<dim3(M_TOT/4), 256, 0, stream>>>(qb, delta, g2 + l*256, be2 + l*256,
                                                     qpos, qpb, (l==NLAY-1) ? (float*)d_out : nullptr);
    }
}